// Round 13
// baseline (901.990 us; speedup 1.0000x reference)
//
#include <hip/hip_runtime.h>

typedef __attribute__((ext_vector_type(4))) float f32x4;
typedef __attribute__((ext_vector_type(4))) int   i32x4;
typedef __attribute__((ext_vector_type(8))) short s16x8;

#define MFMA16(a, b, c)  __builtin_amdgcn_mfma_f32_16x16x32_bf16((a), (b), (c), 0, 0, 0)
#define MFMAI8(a, b, c)  __builtin_amdgcn_mfma_i32_16x16x64_i8((a), (b), (c), 0, 0, 0)

#define QINV (1.0f / 252.0f)

// global->LDS async copy, 16B/lane; LDS dest wave-uniform base (+lane*16 implicit).
typedef __attribute__((address_space(3))) unsigned int lds_uint;
typedef const __attribute__((address_space(1))) unsigned int glob_uint;
__device__ __forceinline__ void glds16(const void* g, void* l) {
    __builtin_amdgcn_global_load_lds((glob_uint*)g, (lds_uint*)l, 16, 0, 0);
}

// ---------- bf16 helpers (RNE) ----------
__device__ inline unsigned short f2bf(float f) {
    unsigned int u = __float_as_uint(f);
    return (unsigned short)((u + 0x7FFFu + ((u >> 16) & 1u)) >> 16);
}
__device__ inline float bf2f(unsigned short b) {
    return __uint_as_float(((unsigned int)b) << 16);
}

// ---------- pack W [K][1024] f32 -> THREE bf16 levels (W_in path) ----------
__global__ __launch_bounds__(256) void k_pack3(const float* __restrict__ W,
                                               unsigned short* __restrict__ L1,
                                               unsigned short* __restrict__ L2,
                                               unsigned short* __restrict__ L3,
                                               int K) {
    int idx = blockIdx.x * 256 + threadIdx.x;
    if (idx >= K * 1024) return;
    int k = idx >> 10;
    int n = idx & 1023;
    float x = W[idx];
    unsigned short h1 = f2bf(x);  float r1 = x - bf2f(h1);
    unsigned short h2 = f2bf(r1); float r2 = r1 - bf2f(h2);
    unsigned short h3 = f2bf(r2);
    size_t o = ((size_t)(k >> 5) << 15) + ((size_t)n << 5) + (k & 31);
    L1[o] = h1; L2[o] = h2; L3[o] = h3;
}

// ---------- per-column max|W_rec| -> t1[n] = max/126 ----------
__global__ __launch_bounds__(256) void k_colmax(const float* __restrict__ W,
                                                float* __restrict__ t1) {
    __shared__ float red[256];
    int n = blockIdx.x;
    float m = 0.f;
    for (int k = threadIdx.x; k < 1024; k += 256)
        m = fmaxf(m, fabsf(W[(size_t)k * 1024 + n]));
    red[threadIdx.x] = m;
    __syncthreads();
    for (int s = 128; s > 0; s >>= 1) {
        if (threadIdx.x < s) red[threadIdx.x] = fmaxf(red[threadIdx.x], red[threadIdx.x + s]);
        __syncthreads();
    }
    if (threadIdx.x == 0) t1[n] = fmaxf(red[0], 1e-30f) * (1.0f / 126.0f);
}

// ---------- pack W_rec -> 3 i8 digits as MFMA-ready 1KB frags ----------
// frag id = (kt*64 + cg)*3 + lvl ; within frag, byte = lane*16 + j where
// lane = ((k>>4)&3)*16 + (n&15), j = k&15  (exact mfma_i32_16x16x64_i8 B layout,
// cols cg*16..cg*16+15, k = kt*64..+63). Every frag is 1KB CONTIGUOUS.
__global__ __launch_bounds__(256) void k_packq(const float* __restrict__ W,
                                               const float* __restrict__ t1a,
                                               signed char* __restrict__ Q) {
    int idx = blockIdx.x * 256 + threadIdx.x;   // k*1024 + n
    int k = idx >> 10;
    int n = idx & 1023;
    float x = W[idx];
    float T1 = t1a[n];
    float T2 = T1 * QINV;
    float T3 = T2 * QINV;
    float q1 = rintf(x / T1);  float r1 = fmaf(-q1, T1, x);
    float q2 = rintf(r1 / T2); float r2 = fmaf(-q2, T2, r1);
    float q3 = rintf(r2 / T3);
    int kt = k >> 6, cg = n >> 4;
    int lane = (((k >> 4) & 3) << 4) | (n & 15);
    size_t base = ((size_t)((kt * 64 + cg) * 3)) << 10;
    size_t lj = (size_t)lane * 16 + (k & 15);
    Q[base + lj]        = (signed char)(int)q1;
    Q[base + 1024 + lj] = (signed char)(int)q2;
    Q[base + 2048 + lj] = (signed char)(int)q3;
}

// ---------- main: 128 blocks x 16 rows, 512 thr (8 waves, 2 waves/SIMD) ----------
// Per step: two col-passes (g=0: cols 0-511, g=1: 512-1023) REUSING acc[4][3]
// (48 AGPR). B-frags stream through a wave-private 12-slot x 1KB LDS ring via
// global_load_lds, GROUP-BATCHED: one vmcnt(9) wait + 3 ds_reads + 3 MFMAs +
// 3 re-issues per nt-group (amortizes LDS latency 3x vs R12's per-frag wait).
#define FSTR 770
#define LDS_SPK0   0        // i8 [16][1024] XOR-swizzled, buf0
#define LDS_SPK1   16384    // buf1
#define LDS_DEC    32768    // f32[1024]
#define LDS_FRQ    36864
#define LDS_T1     40960
#define LDS_RING   45056    // 8 waves x 12288 B (12 slots x 1 KB) -> 143360
#define LDS_FUSED  32768    // f32 [16][770] (phases A/B only; dies before params)
#define LDS_PLDS   45056    // f32 [16][1028] (phase D; ring dead)
#define LDS_TOTAL  143360

// macros reference locals: ring, lane16, Af, acc, inext (inext has NO lane16;
// the macro adds it exactly once).
#define RING_GROUP(nt)                                                         \
    {                                                                          \
        asm volatile("s_waitcnt vmcnt(9)" ::: "memory");                       \
        __builtin_amdgcn_sched_barrier(0);                                     \
        i32x4 Bv0 = *(const i32x4*)(ring + ((nt)*3 + 0) * 1024 + lane16);      \
        i32x4 Bv1 = *(const i32x4*)(ring + ((nt)*3 + 1) * 1024 + lane16);      \
        i32x4 Bv2 = *(const i32x4*)(ring + ((nt)*3 + 2) * 1024 + lane16);      \
        acc[nt][0] = MFMAI8(Af, Bv0, acc[nt][0]);                              \
        acc[nt][1] = MFMAI8(Af, Bv1, acc[nt][1]);                              \
        acc[nt][2] = MFMAI8(Af, Bv2, acc[nt][2]);                              \
        __builtin_amdgcn_sched_barrier(0);                                     \
        glds16(inext + ((nt)*3 + 0) * 1024 + lane16, ring + ((nt)*3 + 0) * 1024); \
        glds16(inext + ((nt)*3 + 1) * 1024 + lane16, ring + ((nt)*3 + 1) * 1024); \
        glds16(inext + ((nt)*3 + 2) * 1024 + lane16, ring + ((nt)*3 + 2) * 1024); \
    }
#define RING_GLAST(nt, N)                                                      \
    {                                                                          \
        asm volatile("s_waitcnt vmcnt(" #N ")" ::: "memory");                  \
        __builtin_amdgcn_sched_barrier(0);                                     \
        i32x4 Bv0 = *(const i32x4*)(ring + ((nt)*3 + 0) * 1024 + lane16);      \
        i32x4 Bv1 = *(const i32x4*)(ring + ((nt)*3 + 1) * 1024 + lane16);      \
        i32x4 Bv2 = *(const i32x4*)(ring + ((nt)*3 + 2) * 1024 + lane16);      \
        acc[nt][0] = MFMAI8(Af, Bv0, acc[nt][0]);                              \
        acc[nt][1] = MFMAI8(Af, Bv1, acc[nt][1]);                              \
        acc[nt][2] = MFMAI8(Af, Bv2, acc[nt][2]);                              \
    }

__global__ __launch_bounds__(512, 2) void k_main(const float* __restrict__ fused,
                                                 const unsigned short* __restrict__ Wi1,
                                                 const unsigned short* __restrict__ Wi2,
                                                 const unsigned short* __restrict__ Wi3,
                                                 const float* __restrict__ b_in,
                                                 const signed char* __restrict__ WrQ,
                                                 const float* __restrict__ t1a,
                                                 const float* __restrict__ b_rec,
                                                 const float* __restrict__ rdec,
                                                 const float* __restrict__ rfrq,
                                                 const float* __restrict__ W_out,
                                                 const float* __restrict__ b_out,
                                                 float* __restrict__ out) {
    extern __shared__ __align__(16) char smem[];
    const int tid = threadIdx.x;
    const int w = tid >> 6, lane = tid & 63;
    const int llo = lane & 15, lhi = lane >> 4;
    const int r0 = blockIdx.x * 16;
    const int lane16 = lane * 16;

    // ---- phase A: stage fused[r0:r0+16][0:768] -> LDS ----
    float* fl = (float*)(smem + LDS_FUSED);
    for (int i = tid; i < 16 * 768; i += 512) {
        int rr = i / 768, cc = i - rr * 768;
        fl[rr * FSTR + cc] = fused[(size_t)(r0 + rr) * 768 + cc];
    }
    __syncthreads();

    // ---- phase B: base = fused @ W_in + b_in (3x3-level bf16, 6 passes) ----
    f32x4 bacc[2][4] = {};
    for (int kt = 0; kt < 24; ++kt) {
        const float* ap = fl + llo * FSTR + kt * 32 + lhi * 8;
        s16x8 a1v, a2v, a3v;
#pragma unroll
        for (int j = 0; j < 8; ++j) {
            float x = ap[j];
            unsigned short h1 = f2bf(x);  float r1 = x - bf2f(h1);
            unsigned short h2 = f2bf(r1); float r2 = r1 - bf2f(h2);
            a1v[j] = (short)h1; a2v[j] = (short)h2; a3v[j] = (short)f2bf(r2);
        }
#pragma unroll
        for (int g = 0; g < 2; ++g) {
#pragma unroll
            for (int nt = 0; nt < 4; ++nt) {
                int c = g * 512 + w * 64 + nt * 16 + llo;
                size_t boff = ((size_t)(kt * 1024 + c) << 5) + lhi * 8;
                s16x8 b1 = *(const s16x8*)&Wi1[boff];
                s16x8 b2 = *(const s16x8*)&Wi2[boff];
                s16x8 b3 = *(const s16x8*)&Wi3[boff];
                bacc[g][nt] = MFMA16(a1v, b1, bacc[g][nt]);
                bacc[g][nt] = MFMA16(a1v, b2, bacc[g][nt]);
                bacc[g][nt] = MFMA16(a2v, b1, bacc[g][nt]);
                bacc[g][nt] = MFMA16(a2v, b2, bacc[g][nt]);
                bacc[g][nt] = MFMA16(a1v, b3, bacc[g][nt]);
                bacc[g][nt] = MFMA16(a3v, b1, bacc[g][nt]);
            }
        }
    }
    __syncthreads();   // fused dead; region becomes params

    // ---- params ----
    float* ldsDec = (float*)(smem + LDS_DEC);
    float* ldsFrq = (float*)(smem + LDS_FRQ);
    float* ldsT1  = (float*)(smem + LDS_T1);
    for (int c = tid; c < 1024; c += 512) {
        ldsDec[c] = (float)(0.55 + 0.4 / (1.0 + exp(-(double)rdec[c])));
        ldsFrq[c] = (float)(0.10 + 0.9 / (1.0 + exp(-(double)rfrq[c])));
        ldsT1[c]  = t1a[c];
    }

    // ---- base2 in regs; inline t=0; spikes(0) -> SPK0 ----
    float base2[2][4][4];
    float mem[2][4][4], res[2][4][4];
    unsigned int pooled_pk[2][4] = {};
#pragma unroll
    for (int g = 0; g < 2; ++g) {
#pragma unroll
        for (int nt = 0; nt < 4; ++nt) {
            int c = g * 512 + w * 64 + nt * 16 + llo;
            float bb = b_in[c];
            float brv = b_rec[c];
#pragma unroll
            for (int fr = 0; fr < 4; ++fr) {
                int row = lhi * 4 + fr;
                float b0 = __fadd_rn(bacc[g][nt][fr], bb);
                base2[g][nt][fr] = __fadd_rn(b0, brv);
                float m_ = __fadd_rn(0.f, b0);
                int s = (m_ > 1.0f) ? 1 : 0;
                res[g][nt][fr] = 0.f;
                mem[g][nt][fr] = __fadd_rn(m_, -(float)s);
                pooled_pk[g][nt] += (unsigned int)s << (8 * fr);
                *(unsigned char*)(smem + LDS_SPK0 + ((row * 1024 + c) ^ ((row & 7) << 4))) =
                    (unsigned char)s;
            }
        }
    }
    __syncthreads();

    // ---- phase C: steps 1..31 ----
    const int ax = (llo & 7) << 4;
    char* ring = smem + LDS_RING + w * 12288;
    for (int t = 1; t < 32; ++t) {
        const char* ab = smem + ((t - 1) & 1) * 16384 + llo * 1024;
        char* wb = smem + (t & 1) * 16384;

#pragma unroll
        for (int g = 0; g < 2; ++g) {
            i32x4 acc[4][3] = {};
            if (g == 0) {
                // prologue: issue 12 frags of (g0, kt0); source = frag base + lane16
                const signed char* ib =
                    WrQ + (((size_t)(w * 4) * 3) << 10) + lane16;
#pragma unroll
                for (int s = 0; s < 12; ++s)
                    glds16(ib + s * 1024, ring + s * 1024);
            }
            for (int kt = 0; kt < 16; ++kt) {
                i32x4 Af = *(const i32x4*)(ab + ((kt * 64 + lhi * 16) ^ ax));
                if (kt < 15 || g == 0) {
                    // next-kt frag base, NO lane16 (macro adds it once)
                    const int nkt = (kt < 15) ? kt + 1 : 0;
                    const int ng  = (kt < 15) ? g : 1;
                    const signed char* inext =
                        WrQ + (((size_t)(nkt * 64 + ng * 32 + w * 4) * 3) << 10);
                    RING_GROUP(0) RING_GROUP(1) RING_GROUP(2) RING_GROUP(3)
                } else {
                    RING_GLAST(0, 9) RING_GLAST(1, 6) RING_GLAST(2, 3) RING_GLAST(3, 0)
                }
            }
            // state update, group g (exact np op order)
#pragma unroll
            for (int nt = 0; nt < 4; ++nt) {
                int c = g * 512 + w * 64 + nt * 16 + llo;
                float dcc = ldsDec[c], fqc = ldsFrq[c], t1c = ldsT1[c];
#pragma unroll
                for (int fr = 0; fr < 4; ++fr) {
                    int row = lhi * 4 + fr;
                    float s3 = (float)acc[nt][2][fr];
                    float s2 = fmaf(s3, QINV, (float)acc[nt][1][fr]);
                    float rec = __fmul_rn(fmaf(s2, QINV, (float)acc[nt][0][fr]), t1c);
                    float drive = __fadd_rn(base2[g][nt][fr], rec);
                    float rnew = __fadd_rn(__fmul_rn(dcc, res[g][nt][fr]),
                                           __fmul_rn(fqc, mem[g][nt][fr]));
                    float tt = __fadd_rn(__fmul_rn(dcc, mem[g][nt][fr]), drive);
                    float m_ = __fadd_rn(tt, -rnew);
                    int s = (m_ > 1.0f) ? 1 : 0;
                    res[g][nt][fr] = rnew;
                    mem[g][nt][fr] = __fadd_rn(m_, -(float)s);
                    pooled_pk[g][nt] += (unsigned int)s << (8 * fr);
                    *(unsigned char*)(wb + ((row * 1024 + c) ^ ((row & 7) << 4))) =
                        (unsigned char)s;
                }
            }
        }
        __syncthreads();
    }

    // ---- phase D: pooled/32 -> LDS (ring region, dead), f64 dot W_out ----
    float* plds = (float*)(smem + LDS_PLDS);
#pragma unroll
    for (int g = 0; g < 2; ++g)
#pragma unroll
        for (int nt = 0; nt < 4; ++nt) {
            int c = g * 512 + w * 64 + nt * 16 + llo;
#pragma unroll
            for (int fr = 0; fr < 4; ++fr)
                plds[(lhi * 4 + fr) * 1028 + c] =
                    (float)((pooled_pk[g][nt] >> (8 * fr)) & 255u) * 0.03125f;
        }
    __syncthreads();
    if (tid < 256) {
        int row = tid >> 4, o = tid & 15;
        double s = 0.0;
        for (int h = 0; h < 1024; ++h)
            s += (double)plds[row * 1028 + h] * (double)W_out[h * 16 + o];
        out[(size_t)(r0 + row) * 16 + o] = __fadd_rn((float)s, b_out[o]);
    }
}

extern "C" void kernel_launch(void* const* d_in, const int* in_sizes, int n_in,
                              void* d_out, int out_size, void* d_ws, size_t ws_size,
                              hipStream_t stream) {
    const float* fused = (const float*)d_in[0];
    const float* W_in  = (const float*)d_in[1];
    const float* b_in  = (const float*)d_in[2];
    const float* W_rec = (const float*)d_in[3];
    const float* b_rec = (const float*)d_in[4];
    const float* W_out = (const float*)d_in[5];
    const float* b_out = (const float*)d_in[6];
    const float* rdec  = (const float*)d_in[7];
    const float* rfrq  = (const float*)d_in[8];

    // ws: WrQ 3MB | t1 4KB | Wi1/2/3 4.5MB  (total ~7.75MB)
    char* ws = (char*)d_ws;
    signed char*    WrQ = (signed char*)(ws);
    float*          t1a = (float*)(ws + (3u << 20));
    unsigned short* Wi1 = (unsigned short*)(ws + (3u << 20) + (1u << 18));
    unsigned short* Wi2 = (unsigned short*)(ws + (3u << 20) + (1u << 18) + (3u << 19));
    unsigned short* Wi3 = (unsigned short*)(ws + (3u << 20) + (1u << 18) + (6u << 19));
    float* out = (float*)d_out;

    hipFuncSetAttribute((const void*)k_main,
                        hipFuncAttributeMaxDynamicSharedMemorySize, LDS_TOTAL);

    hipLaunchKernelGGL(k_colmax, dim3(1024), dim3(256), 0, stream, W_rec, t1a);
    hipLaunchKernelGGL(k_packq, dim3(4096), dim3(256), 0, stream, W_rec, t1a, WrQ);
    hipLaunchKernelGGL(k_pack3, dim3(3072), dim3(256), 0, stream, W_in, Wi1, Wi2, Wi3, 768);
    hipLaunchKernelGGL(k_main, dim3(128), dim3(512), LDS_TOTAL, stream,
                       fused, Wi1, Wi2, Wi3, b_in, WrQ, t1a, b_rec,
                       rdec, rfrq, W_out, b_out, out);
}

// Round 14
// 697.503 us; speedup vs baseline: 1.2932x; 1.2932x over previous
//
#include <hip/hip_runtime.h>

typedef __attribute__((ext_vector_type(4))) float f32x4;
typedef __attribute__((ext_vector_type(4))) int   i32x4;
typedef __attribute__((ext_vector_type(8))) short s16x8;

#define MFMA16(a, b, c)  __builtin_amdgcn_mfma_f32_16x16x32_bf16((a), (b), (c), 0, 0, 0)
#define MFMAI8(a, b, c)  __builtin_amdgcn_mfma_i32_16x16x64_i8((a), (b), (c), 0, 0, 0)

#define QINV (1.0f / 252.0f)

// global->LDS async copy, 16B/lane; LDS dest wave-uniform base (+lane*16 implicit).
typedef __attribute__((address_space(3))) unsigned int lds_uint;
typedef const __attribute__((address_space(1))) unsigned int glob_uint;
__device__ __forceinline__ void glds16(const void* g, void* l) {
    __builtin_amdgcn_global_load_lds((glob_uint*)g, (lds_uint*)l, 16, 0, 0);
}

// ---------- bf16 helpers (RNE) ----------
__device__ inline unsigned short f2bf(float f) {
    unsigned int u = __float_as_uint(f);
    return (unsigned short)((u + 0x7FFFu + ((u >> 16) & 1u)) >> 16);
}
__device__ inline float bf2f(unsigned short b) {
    return __uint_as_float(((unsigned int)b) << 16);
}

// ---------- pack W [K][1024] f32 -> THREE bf16 levels (W_in path) ----------
__global__ __launch_bounds__(256) void k_pack3(const float* __restrict__ W,
                                               unsigned short* __restrict__ L1,
                                               unsigned short* __restrict__ L2,
                                               unsigned short* __restrict__ L3,
                                               int K) {
    int idx = blockIdx.x * 256 + threadIdx.x;
    if (idx >= K * 1024) return;
    int k = idx >> 10;
    int n = idx & 1023;
    float x = W[idx];
    unsigned short h1 = f2bf(x);  float r1 = x - bf2f(h1);
    unsigned short h2 = f2bf(r1); float r2 = r1 - bf2f(h2);
    unsigned short h3 = f2bf(r2);
    size_t o = ((size_t)(k >> 5) << 15) + ((size_t)n << 5) + (k & 31);
    L1[o] = h1; L2[o] = h2; L3[o] = h3;
}

// ---------- per-column max|W_rec| -> t1[n] = max/126 ----------
__global__ __launch_bounds__(256) void k_colmax(const float* __restrict__ W,
                                                float* __restrict__ t1) {
    __shared__ float red[256];
    int n = blockIdx.x;
    float m = 0.f;
    for (int k = threadIdx.x; k < 1024; k += 256)
        m = fmaxf(m, fabsf(W[(size_t)k * 1024 + n]));
    red[threadIdx.x] = m;
    __syncthreads();
    for (int s = 128; s > 0; s >>= 1) {
        if (threadIdx.x < s) red[threadIdx.x] = fmaxf(red[threadIdx.x], red[threadIdx.x + s]);
        __syncthreads();
    }
    if (threadIdx.x == 0) t1[n] = fmaxf(red[0], 1e-30f) * (1.0f / 126.0f);
}

// ---------- pack W_rec -> 3 i8 digits as MFMA-ready 1KB frags ----------
// frag id = (kt*64 + cg)*3 + lvl ; byte = lane*16 + j, lane = ((k>>4)&3)*16 +
// (n&15), j = k&15 (mfma_i32_16x16x64_i8 B layout). Every frag 1KB contiguous.
__global__ __launch_bounds__(256) void k_packq(const float* __restrict__ W,
                                               const float* __restrict__ t1a,
                                               signed char* __restrict__ Q) {
    int idx = blockIdx.x * 256 + threadIdx.x;   // k*1024 + n
    int k = idx >> 10;
    int n = idx & 1023;
    float x = W[idx];
    float T1 = t1a[n];
    float T2 = T1 * QINV;
    float T3 = T2 * QINV;
    float q1 = rintf(x / T1);  float r1 = fmaf(-q1, T1, x);
    float q2 = rintf(r1 / T2); float r2 = fmaf(-q2, T2, r1);
    float q3 = rintf(r2 / T3);
    int kt = k >> 6, cg = n >> 4;
    int lane = (((k >> 4) & 3) << 4) | (n & 15);
    size_t base = ((size_t)((kt * 64 + cg) * 3)) << 10;
    size_t lj = (size_t)lane * 16 + (k & 15);
    Q[base + lj]        = (signed char)(int)q1;
    Q[base + 1024 + lj] = (signed char)(int)q2;
    Q[base + 2048 + lj] = (signed char)(int)q3;
}

// ---------- main: cooperative 256 blocks x 512 thr; pair (2p,2p+h) = rows
// 16p..16p+16; half h owns cols h*512..+512 (1.5 MB WrQ slab/step via the
// R12 ring). Spikes exchanged pairwise as 1KB bit-masks through L3 (AGENT
// atomics), flag-gated. No grid-wide sync. ----------
#define FSTR 770
#define LDS_SPK0   0        // i8 [16][1024] XOR-swizzled, buf0 (full k range)
#define LDS_SPK1   16384
#define LDS_DEC    32768    // f32[512] own cols
#define LDS_FRQ    34816
#define LDS_T1     36864
#define LDS_RING   40960    // 8 waves x 12288 -> 139264
#define LDS_FUSED  32768    // f32 [16][770] (phases A/B only)
#define LDS_PLDS   40960    // f32 [16][520] (phase D; ring dead)
#define LDS_TOTAL  139264

#define RING_GROUP(nt)                                                         \
    {                                                                          \
        asm volatile("s_waitcnt vmcnt(9)" ::: "memory");                       \
        __builtin_amdgcn_sched_barrier(0);                                     \
        i32x4 Bv0 = *(const i32x4*)(ring + ((nt)*3 + 0) * 1024 + lane16);      \
        i32x4 Bv1 = *(const i32x4*)(ring + ((nt)*3 + 1) * 1024 + lane16);      \
        i32x4 Bv2 = *(const i32x4*)(ring + ((nt)*3 + 2) * 1024 + lane16);      \
        acc[nt][0] = MFMAI8(Af, Bv0, acc[nt][0]);                              \
        acc[nt][1] = MFMAI8(Af, Bv1, acc[nt][1]);                              \
        acc[nt][2] = MFMAI8(Af, Bv2, acc[nt][2]);                              \
        __builtin_amdgcn_sched_barrier(0);                                     \
        glds16(inext + ((nt)*3 + 0) * 1024 + lane16, ring + ((nt)*3 + 0) * 1024); \
        glds16(inext + ((nt)*3 + 1) * 1024 + lane16, ring + ((nt)*3 + 1) * 1024); \
        glds16(inext + ((nt)*3 + 2) * 1024 + lane16, ring + ((nt)*3 + 2) * 1024); \
    }
#define RING_GLAST(nt, N)                                                      \
    {                                                                          \
        asm volatile("s_waitcnt vmcnt(" #N ")" ::: "memory");                  \
        __builtin_amdgcn_sched_barrier(0);                                     \
        i32x4 Bv0 = *(const i32x4*)(ring + ((nt)*3 + 0) * 1024 + lane16);      \
        i32x4 Bv1 = *(const i32x4*)(ring + ((nt)*3 + 1) * 1024 + lane16);      \
        i32x4 Bv2 = *(const i32x4*)(ring + ((nt)*3 + 2) * 1024 + lane16);      \
        acc[nt][0] = MFMAI8(Af, Bv0, acc[nt][0]);                              \
        acc[nt][1] = MFMAI8(Af, Bv1, acc[nt][1]);                              \
        acc[nt][2] = MFMAI8(Af, Bv2, acc[nt][2]);                              \
    }

__global__ __launch_bounds__(512, 2) void k_main(const float* __restrict__ fused,
                                                 const unsigned short* __restrict__ Wi1,
                                                 const unsigned short* __restrict__ Wi2,
                                                 const unsigned short* __restrict__ Wi3,
                                                 const float* __restrict__ b_in,
                                                 const signed char* __restrict__ WrQ,
                                                 const float* __restrict__ t1a,
                                                 const float* __restrict__ b_rec,
                                                 const float* __restrict__ rdec,
                                                 const float* __restrict__ rfrq,
                                                 const float* __restrict__ W_out,
                                                 const float* __restrict__ b_out,
                                                 char* __restrict__ sx,
                                                 unsigned long long* __restrict__ pdb,
                                                 unsigned int* __restrict__ flags,
                                                 float* __restrict__ out) {
    extern __shared__ __align__(16) char smem[];
    const int tid = threadIdx.x;
    const int w = tid >> 6, lane = tid & 63;
    const int llo = lane & 15, lhi = lane >> 4;
    const int bid = blockIdx.x;
    const int pair = bid >> 1, h = bid & 1;
    const int r0 = pair * 16;
    const int cbase = h * 512;
    const int pbase = 512 - cbase;
    const int lane16 = lane * 16;

    // ---- phase A: stage fused[r0:r0+16][0:768] -> LDS ----
    float* fl = (float*)(smem + LDS_FUSED);
    for (int i = tid; i < 16 * 768; i += 512) {
        int rr = i / 768, cc = i - rr * 768;
        fl[rr * FSTR + cc] = fused[(size_t)(r0 + rr) * 768 + cc];
    }
    __syncthreads();

    // ---- phase B: base for own 512 cols (3x3-level bf16, 6 passes) ----
    f32x4 bacc[4] = {};
    for (int kt = 0; kt < 24; ++kt) {
        const float* ap = fl + llo * FSTR + kt * 32 + lhi * 8;
        s16x8 a1v, a2v, a3v;
#pragma unroll
        for (int j = 0; j < 8; ++j) {
            float x = ap[j];
            unsigned short h1 = f2bf(x);  float r1 = x - bf2f(h1);
            unsigned short h2 = f2bf(r1); float r2 = r1 - bf2f(h2);
            a1v[j] = (short)h1; a2v[j] = (short)h2; a3v[j] = (short)f2bf(r2);
        }
#pragma unroll
        for (int nt = 0; nt < 4; ++nt) {
            int c = cbase + w * 64 + nt * 16 + llo;
            size_t boff = ((size_t)(kt * 1024 + c) << 5) + lhi * 8;
            s16x8 b1 = *(const s16x8*)&Wi1[boff];
            s16x8 b2 = *(const s16x8*)&Wi2[boff];
            s16x8 b3 = *(const s16x8*)&Wi3[boff];
            bacc[nt] = MFMA16(a1v, b1, bacc[nt]);
            bacc[nt] = MFMA16(a1v, b2, bacc[nt]);
            bacc[nt] = MFMA16(a2v, b1, bacc[nt]);
            bacc[nt] = MFMA16(a2v, b2, bacc[nt]);
            bacc[nt] = MFMA16(a1v, b3, bacc[nt]);
            bacc[nt] = MFMA16(a3v, b1, bacc[nt]);
        }
    }
    __syncthreads();   // fused dead

    // ---- params (own 512 cols; lc = local col) ----
    float* ldsDec = (float*)(smem + LDS_DEC);
    float* ldsFrq = (float*)(smem + LDS_FRQ);
    float* ldsT1  = (float*)(smem + LDS_T1);
    {
        int lc = tid;          // 512 threads cover 512 local cols
        int c = cbase + lc;
        ldsDec[lc] = (float)(0.55 + 0.4 / (1.0 + exp(-(double)rdec[c])));
        ldsFrq[lc] = (float)(0.10 + 0.9 / (1.0 + exp(-(double)rfrq[c])));
        ldsT1[lc]  = t1a[c];
    }

    // ---- t=0 inline; own spikes -> LDS buf0 + bit-exchange ----
    float base2[4][4];
    float mem[4][4], res[4][4];
    unsigned int pooled_pk[4] = {0, 0, 0, 0};
    unsigned long long bal[16];
#pragma unroll
    for (int nt = 0; nt < 4; ++nt) {
        int lc = w * 64 + nt * 16 + llo;
        int c = cbase + lc;
        float bb = b_in[c];
        float brv = b_rec[c];
#pragma unroll
        for (int fr = 0; fr < 4; ++fr) {
            int row = lhi * 4 + fr;
            float b0 = __fadd_rn(bacc[nt][fr], bb);
            base2[nt][fr] = __fadd_rn(b0, brv);
            float m_ = __fadd_rn(0.f, b0);
            int s = (m_ > 1.0f) ? 1 : 0;
            res[nt][fr] = 0.f;
            mem[nt][fr] = __fadd_rn(m_, -(float)s);
            pooled_pk[nt] += (unsigned int)s << (8 * fr);
            bal[nt * 4 + fr] = __ballot(s);
            *(unsigned char*)(smem + LDS_SPK0 + ((row * 1024 + c) ^ ((row & 7) << 4))) =
                (unsigned char)s;
        }
    }
    if (lane < 16) {
        unsigned long long rb = 0;
#pragma unroll
        for (int nt = 0; nt < 4; ++nt)
            rb |= ((bal[nt * 4 + (lane & 3)] >> (16 * (lane >> 2))) & 0xFFFFull) << (16 * nt);
        __hip_atomic_store((unsigned long long*)(sx + ((0 * 256 + pair * 2 + h) << 10)
                                                 + lane * 64 + w * 8),
                           rb, __ATOMIC_RELAXED, __HIP_MEMORY_SCOPE_AGENT);
    }
    __syncthreads();   // drains all waves' atomic stores
    if (tid == 0)
        __hip_atomic_store(&flags[0 * 256 + pair * 2 + h], 1u,
                           __ATOMIC_RELEASE, __HIP_MEMORY_SCOPE_AGENT);

    // ---- phase C: steps 1..31 ----
    const int ax = (llo & 7) << 4;
    char* ring = smem + LDS_RING + w * 12288;
    for (int t = 1; t < 32; ++t) {
        // wait partner spikes(t-1), stage bits -> A-LDS partner half
        if (tid == 0) {
            while (__hip_atomic_load(&flags[(t - 1) * 256 + pair * 2 + (1 - h)],
                                     __ATOMIC_ACQUIRE, __HIP_MEMORY_SCOPE_AGENT) == 0)
                __builtin_amdgcn_s_sleep(2);
        }
        __syncthreads();
        if (tid < 128) {
            int row = tid >> 3, pc = tid & 7;
            unsigned long long bits = __hip_atomic_load(
                (unsigned long long*)(sx + ((((t - 1) & 1) * 256 + pair * 2 + (1 - h)) << 10)
                                      + row * 64 + pc * 8),
                __ATOMIC_RELAXED, __HIP_MEMORY_SCOPE_AGENT);
            int sw = (row & 7) << 4;
            char* dst = smem + ((t - 1) & 1) * 16384;
            int kb = pbase + pc * 64;
#pragma unroll
            for (int c4 = 0; c4 < 4; ++c4) {
                unsigned int wb16 = (unsigned int)(bits >> (c4 * 16)) & 0xFFFFu;
                i32x4 v;
#pragma unroll
                for (int q = 0; q < 4; ++q) {
                    unsigned int b4 = (wb16 >> (q * 4)) & 0xFu;
                    v[q] = (int)((b4 & 1u) | ((b4 >> 1) & 1u) << 8 |
                                 ((b4 >> 2) & 1u) << 16 | ((b4 >> 3) & 1u) << 24);
                }
                *(i32x4*)(dst + ((row * 1024 + kb + c4 * 16) ^ sw)) = v;
            }
        }
        __syncthreads();

        const char* ab = smem + ((t - 1) & 1) * 16384 + llo * 1024;
        char* wbuf = smem + (t & 1) * 16384;

        i32x4 acc[4][3] = {};
        {   // prologue: 12 frags of kt0 (own slab)
            const signed char* ib =
                WrQ + (((size_t)((h * 32 + w * 4) * 3)) << 10) + lane16;
#pragma unroll
            for (int s = 0; s < 12; ++s)
                glds16(ib + s * 1024, ring + s * 1024);
        }
        for (int kt = 0; kt < 16; ++kt) {
            i32x4 Af = *(const i32x4*)(ab + ((kt * 64 + lhi * 16) ^ ax));
            if (kt < 15) {
                const signed char* inext =
                    WrQ + (((size_t)(((kt + 1) * 64 + h * 32 + w * 4) * 3)) << 10);
                RING_GROUP(0) RING_GROUP(1) RING_GROUP(2) RING_GROUP(3)
            } else {
                RING_GLAST(0, 9) RING_GLAST(1, 6) RING_GLAST(2, 3) RING_GLAST(3, 0)
            }
        }

        // state update (exact np op order) + spike emit
#pragma unroll
        for (int nt = 0; nt < 4; ++nt) {
            int lc = w * 64 + nt * 16 + llo;
            int c = cbase + lc;
            float dcc = ldsDec[lc], fqc = ldsFrq[lc], t1c = ldsT1[lc];
#pragma unroll
            for (int fr = 0; fr < 4; ++fr) {
                int row = lhi * 4 + fr;
                float s3 = (float)acc[nt][2][fr];
                float s2 = fmaf(s3, QINV, (float)acc[nt][1][fr]);
                float rec = __fmul_rn(fmaf(s2, QINV, (float)acc[nt][0][fr]), t1c);
                float drive = __fadd_rn(base2[nt][fr], rec);
                float rnew = __fadd_rn(__fmul_rn(dcc, res[nt][fr]),
                                       __fmul_rn(fqc, mem[nt][fr]));
                float tt = __fadd_rn(__fmul_rn(dcc, mem[nt][fr]), drive);
                float m_ = __fadd_rn(tt, -rnew);
                int s = (m_ > 1.0f) ? 1 : 0;
                res[nt][fr] = rnew;
                mem[nt][fr] = __fadd_rn(m_, -(float)s);
                pooled_pk[nt] += (unsigned int)s << (8 * fr);
                bal[nt * 4 + fr] = __ballot(s);
                *(unsigned char*)(wbuf + ((row * 1024 + c) ^ ((row & 7) << 4))) =
                    (unsigned char)s;
            }
        }
        if (lane < 16) {
            unsigned long long rb = 0;
#pragma unroll
            for (int nt = 0; nt < 4; ++nt)
                rb |= ((bal[nt * 4 + (lane & 3)] >> (16 * (lane >> 2))) & 0xFFFFull) << (16 * nt);
            __hip_atomic_store((unsigned long long*)(sx + (((t & 1) * 256 + pair * 2 + h) << 10)
                                                     + lane * 64 + w * 8),
                               rb, __ATOMIC_RELAXED, __HIP_MEMORY_SCOPE_AGENT);
        }
        __syncthreads();
        if (tid == 0)
            __hip_atomic_store(&flags[t * 256 + pair * 2 + h], 1u,
                               __ATOMIC_RELEASE, __HIP_MEMORY_SCOPE_AGENT);
    }

    // ---- phase D: own-half f64 partial; h=1 ships bits; h=0 combines ----
    float* plds = (float*)(smem + LDS_PLDS);
#pragma unroll
    for (int nt = 0; nt < 4; ++nt) {
        int lc = w * 64 + nt * 16 + llo;
#pragma unroll
        for (int fr = 0; fr < 4; ++fr)
            plds[(lhi * 4 + fr) * 520 + lc] =
                (float)((pooled_pk[nt] >> (8 * fr)) & 255u) * 0.03125f;
    }
    __syncthreads();
    double part = 0.0;
    if (tid < 256) {
        int row = tid >> 4, o = tid & 15;
        for (int j = 0; j < 512; ++j)
            part += (double)plds[row * 520 + j] * (double)W_out[(size_t)(cbase + j) * 16 + o];
    }
    if (h == 1) {
        if (tid < 256)
            __hip_atomic_store(&pdb[pair * 256 + tid], __double_as_longlong(part),
                               __ATOMIC_RELAXED, __HIP_MEMORY_SCOPE_AGENT);
        __syncthreads();
        if (tid == 0)
            __hip_atomic_store(&flags[32 * 256 + pair * 2 + 1], 1u,
                               __ATOMIC_RELEASE, __HIP_MEMORY_SCOPE_AGENT);
    } else {
        if (tid == 0) {
            while (__hip_atomic_load(&flags[32 * 256 + pair * 2 + 1],
                                     __ATOMIC_ACQUIRE, __HIP_MEMORY_SCOPE_AGENT) == 0)
                __builtin_amdgcn_s_sleep(2);
        }
        __syncthreads();
        if (tid < 256) {
            int row = tid >> 4, o = tid & 15;
            unsigned long long pb = __hip_atomic_load(&pdb[pair * 256 + tid],
                                                      __ATOMIC_RELAXED,
                                                      __HIP_MEMORY_SCOPE_AGENT);
            double tot = part + __longlong_as_double(pb);
            out[(size_t)(r0 + row) * 16 + o] = __fadd_rn((float)tot, b_out[o]);
        }
    }
}

extern "C" void kernel_launch(void* const* d_in, const int* in_sizes, int n_in,
                              void* d_out, int out_size, void* d_ws, size_t ws_size,
                              hipStream_t stream) {
    const float* fused = (const float*)d_in[0];
    const float* W_in  = (const float*)d_in[1];
    const float* b_in  = (const float*)d_in[2];
    const float* W_rec = (const float*)d_in[3];
    const float* b_rec = (const float*)d_in[4];
    const float* W_out = (const float*)d_in[5];
    const float* b_out = (const float*)d_in[6];
    const float* rdec  = (const float*)d_in[7];
    const float* rfrq  = (const float*)d_in[8];

    // ws: WrQ 3MB | t1 | Wi1/2/3 4.5MB | sx 512KB | pdb 256KB | flags 36KB  (~8.6MB)
    char* ws = (char*)d_ws;
    signed char*        WrQ   = (signed char*)(ws);
    float*              t1a   = (float*)(ws + 3145728);
    unsigned short*     Wi1   = (unsigned short*)(ws + 3407872);
    unsigned short*     Wi2   = (unsigned short*)(ws + 4980736);
    unsigned short*     Wi3   = (unsigned short*)(ws + 6553600);
    char*               sx    = ws + 8126464;
    unsigned long long* pdb   = (unsigned long long*)(ws + 8650752);
    unsigned int*       flags = (unsigned int*)(ws + 8912896);
    float* out = (float*)d_out;

    hipFuncSetAttribute((const void*)k_main,
                        hipFuncAttributeMaxDynamicSharedMemorySize, LDS_TOTAL);

    hipMemsetAsync(flags, 0, 33 * 256 * 4, stream);
    hipLaunchKernelGGL(k_colmax, dim3(1024), dim3(256), 0, stream, W_rec, t1a);
    hipLaunchKernelGGL(k_packq, dim3(4096), dim3(256), 0, stream, W_rec, t1a, WrQ);
    hipLaunchKernelGGL(k_pack3, dim3(3072), dim3(256), 0, stream, W_in, Wi1, Wi2, Wi3, 768);

    void* args[] = {(void*)&fused, (void*)&Wi1, (void*)&Wi2, (void*)&Wi3, (void*)&b_in,
                    (void*)&WrQ, (void*)&t1a, (void*)&b_rec, (void*)&rdec, (void*)&rfrq,
                    (void*)&W_out, (void*)&b_out, (void*)&sx, (void*)&pdb, (void*)&flags,
                    (void*)&out};
    hipLaunchCooperativeKernel((void*)k_main, dim3(256), dim3(512), args, LDS_TOTAL, stream);
}

// Round 15
// 656.061 us; speedup vs baseline: 1.3749x; 1.0632x over previous
//
#include <hip/hip_runtime.h>

typedef __attribute__((ext_vector_type(4))) float f32x4;
typedef __attribute__((ext_vector_type(4))) int   i32x4;
typedef __attribute__((ext_vector_type(8))) short s16x8;

#define MFMA16(a, b, c)  __builtin_amdgcn_mfma_f32_16x16x32_bf16((a), (b), (c), 0, 0, 0)
#define MFMAI8(a, b, c)  __builtin_amdgcn_mfma_i32_16x16x64_i8((a), (b), (c), 0, 0, 0)

#define QINV (1.0f / 252.0f)

typedef __attribute__((address_space(3))) unsigned int lds_uint;
typedef const __attribute__((address_space(1))) unsigned int glob_uint;
__device__ __forceinline__ void glds16(const void* g, void* l) {
    __builtin_amdgcn_global_load_lds((glob_uint*)g, (lds_uint*)l, 16, 0, 0);
}

// raw barriers: LDS-only drain; wave-private DMA ring stays in flight across.
#define SBARL()                                                                \
    {                                                                          \
        __builtin_amdgcn_sched_barrier(0);                                     \
        asm volatile("s_waitcnt lgkmcnt(0)" ::: "memory");                     \
        __builtin_amdgcn_s_barrier();                                          \
        __builtin_amdgcn_sched_barrier(0);                                     \
    }
#define SBAR()                                                                 \
    {                                                                          \
        __builtin_amdgcn_sched_barrier(0);                                     \
        __builtin_amdgcn_s_barrier();                                          \
        __builtin_amdgcn_sched_barrier(0);                                     \
    }

// ---------- bf16 helpers (RNE) ----------
__device__ inline unsigned short f2bf(float f) {
    unsigned int u = __float_as_uint(f);
    return (unsigned short)((u + 0x7FFFu + ((u >> 16) & 1u)) >> 16);
}
__device__ inline float bf2f(unsigned short b) {
    return __uint_as_float(((unsigned int)b) << 16);
}

// ---------- pack W [K][1024] f32 -> THREE bf16 levels (W_in path) ----------
__global__ __launch_bounds__(256) void k_pack3(const float* __restrict__ W,
                                               unsigned short* __restrict__ L1,
                                               unsigned short* __restrict__ L2,
                                               unsigned short* __restrict__ L3,
                                               int K) {
    int idx = blockIdx.x * 256 + threadIdx.x;
    if (idx >= K * 1024) return;
    int k = idx >> 10;
    int n = idx & 1023;
    float x = W[idx];
    unsigned short h1 = f2bf(x);  float r1 = x - bf2f(h1);
    unsigned short h2 = f2bf(r1); float r2 = r1 - bf2f(h2);
    unsigned short h3 = f2bf(r2);
    size_t o = ((size_t)(k >> 5) << 15) + ((size_t)n << 5) + (k & 31);
    L1[o] = h1; L2[o] = h2; L3[o] = h3;
}

// ---------- per-column max|W_rec| -> t1[n] = max/126 ----------
__global__ __launch_bounds__(256) void k_colmax(const float* __restrict__ W,
                                                float* __restrict__ t1) {
    __shared__ float red[256];
    int n = blockIdx.x;
    float m = 0.f;
    for (int k = threadIdx.x; k < 1024; k += 256)
        m = fmaxf(m, fabsf(W[(size_t)k * 1024 + n]));
    red[threadIdx.x] = m;
    __syncthreads();
    for (int s = 128; s > 0; s >>= 1) {
        if (threadIdx.x < s) red[threadIdx.x] = fmaxf(red[threadIdx.x], red[threadIdx.x + s]);
        __syncthreads();
    }
    if (threadIdx.x == 0) t1[n] = fmaxf(red[0], 1e-30f) * (1.0f / 126.0f);
}

// ---------- pack W_rec -> 3 i8 digits as MFMA-ready 1KB frags ----------
__global__ __launch_bounds__(256) void k_packq(const float* __restrict__ W,
                                               const float* __restrict__ t1a,
                                               signed char* __restrict__ Q) {
    int idx = blockIdx.x * 256 + threadIdx.x;   // k*1024 + n
    int k = idx >> 10;
    int n = idx & 1023;
    float x = W[idx];
    float T1 = t1a[n];
    float T2 = T1 * QINV;
    float T3 = T2 * QINV;
    float q1 = rintf(x / T1);  float r1 = fmaf(-q1, T1, x);
    float q2 = rintf(r1 / T2); float r2 = fmaf(-q2, T2, r1);
    float q3 = rintf(r2 / T3);
    int kt = k >> 6, cg = n >> 4;
    int lane = (((k >> 4) & 3) << 4) | (n & 15);
    size_t base = ((size_t)((kt * 64 + cg) * 3)) << 10;
    size_t lj = (size_t)lane * 16 + (k & 15);
    Q[base + lj]        = (signed char)(int)q1;
    Q[base + 1024 + lj] = (signed char)(int)q2;
    Q[base + 2048 + lj] = (signed char)(int)q3;
}

#define FSTR 770
#define LDS_SPK0   0
#define LDS_SPK1   16384
#define LDS_DEC    32768
#define LDS_FRQ    34816
#define LDS_T1     36864
#define LDS_RING   40960
#define LDS_FUSED  32768
#define LDS_PLDS   40960
#define LDS_TOTAL  139264

#define RING_GROUP(nt)                                                         \
    {                                                                          \
        asm volatile("s_waitcnt vmcnt(9)" ::: "memory");                       \
        __builtin_amdgcn_sched_barrier(0);                                     \
        i32x4 Bv0 = *(const i32x4*)(ring + ((nt)*3 + 0) * 1024 + lane16);      \
        i32x4 Bv1 = *(const i32x4*)(ring + ((nt)*3 + 1) * 1024 + lane16);      \
        i32x4 Bv2 = *(const i32x4*)(ring + ((nt)*3 + 2) * 1024 + lane16);      \
        acc[nt][0] = MFMAI8(Af, Bv0, acc[nt][0]);                              \
        acc[nt][1] = MFMAI8(Af, Bv1, acc[nt][1]);                              \
        acc[nt][2] = MFMAI8(Af, Bv2, acc[nt][2]);                              \
        __builtin_amdgcn_sched_barrier(0);                                     \
        glds16(inext + ((nt)*3 + 0) * 1024 + lane16, ring + ((nt)*3 + 0) * 1024); \
        glds16(inext + ((nt)*3 + 1) * 1024 + lane16, ring + ((nt)*3 + 1) * 1024); \
        glds16(inext + ((nt)*3 + 2) * 1024 + lane16, ring + ((nt)*3 + 2) * 1024); \
    }
#define RING_GLAST(nt, N)                                                      \
    {                                                                          \
        asm volatile("s_waitcnt vmcnt(" #N ")" ::: "memory");                  \
        __builtin_amdgcn_sched_barrier(0);                                     \
        i32x4 Bv0 = *(const i32x4*)(ring + ((nt)*3 + 0) * 1024 + lane16);      \
        i32x4 Bv1 = *(const i32x4*)(ring + ((nt)*3 + 1) * 1024 + lane16);      \
        i32x4 Bv2 = *(const i32x4*)(ring + ((nt)*3 + 2) * 1024 + lane16);      \
        acc[nt][0] = MFMAI8(Af, Bv0, acc[nt][0]);                              \
        acc[nt][1] = MFMAI8(Af, Bv1, acc[nt][1]);                              \
        acc[nt][2] = MFMAI8(Af, Bv2, acc[nt][2]);                              \
    }

__global__ __launch_bounds__(512, 2) void k_main(const float* __restrict__ fused,
                                                 const unsigned short* __restrict__ Wi1,
                                                 const unsigned short* __restrict__ Wi2,
                                                 const unsigned short* __restrict__ Wi3,
                                                 const float* __restrict__ b_in,
                                                 const signed char* __restrict__ WrQ,
                                                 const float* __restrict__ t1a,
                                                 const float* __restrict__ b_rec,
                                                 const float* __restrict__ rdec,
                                                 const float* __restrict__ rfrq,
                                                 const float* __restrict__ W_out,
                                                 const float* __restrict__ b_out,
                                                 char* __restrict__ sx,
                                                 unsigned long long* __restrict__ pdb,
                                                 unsigned int* __restrict__ flags,
                                                 float* __restrict__ out) {
    extern __shared__ __align__(16) char smem[];
    const int tid = threadIdx.x;
    const int w = tid >> 6, lane = tid & 63;
    const int llo = lane & 15, lhi = lane >> 4;
    const int bid = blockIdx.x;
    const int pair = bid >> 1, h = bid & 1;
    const int r0 = pair * 16;
    const int cbase = h * 512;
    const int pbase = 512 - cbase;
    const int lane16 = lane * 16;

    // ---- phase A ----
    float* fl = (float*)(smem + LDS_FUSED);
    for (int i = tid; i < 16 * 768; i += 512) {
        int rr = i / 768, cc = i - rr * 768;
        fl[rr * FSTR + cc] = fused[(size_t)(r0 + rr) * 768 + cc];
    }
    __syncthreads();

    // ---- phase B: base for own 512 cols ----
    f32x4 bacc[4] = {};
    for (int kt = 0; kt < 24; ++kt) {
        const float* ap = fl + llo * FSTR + kt * 32 + lhi * 8;
        s16x8 a1v, a2v, a3v;
#pragma unroll
        for (int j = 0; j < 8; ++j) {
            float x = ap[j];
            unsigned short h1 = f2bf(x);  float r1 = x - bf2f(h1);
            unsigned short h2 = f2bf(r1); float r2 = r1 - bf2f(h2);
            a1v[j] = (short)h1; a2v[j] = (short)h2; a3v[j] = (short)f2bf(r2);
        }
#pragma unroll
        for (int nt = 0; nt < 4; ++nt) {
            int c = cbase + w * 64 + nt * 16 + llo;
            size_t boff = ((size_t)(kt * 1024 + c) << 5) + lhi * 8;
            s16x8 b1 = *(const s16x8*)&Wi1[boff];
            s16x8 b2 = *(const s16x8*)&Wi2[boff];
            s16x8 b3 = *(const s16x8*)&Wi3[boff];
            bacc[nt] = MFMA16(a1v, b1, bacc[nt]);
            bacc[nt] = MFMA16(a1v, b2, bacc[nt]);
            bacc[nt] = MFMA16(a2v, b1, bacc[nt]);
            bacc[nt] = MFMA16(a2v, b2, bacc[nt]);
            bacc[nt] = MFMA16(a1v, b3, bacc[nt]);
            bacc[nt] = MFMA16(a3v, b1, bacc[nt]);
        }
    }
    __syncthreads();

    // ---- params ----
    float* ldsDec = (float*)(smem + LDS_DEC);
    float* ldsFrq = (float*)(smem + LDS_FRQ);
    float* ldsT1  = (float*)(smem + LDS_T1);
    {
        int lc = tid;
        int c = cbase + lc;
        ldsDec[lc] = (float)(0.55 + 0.4 / (1.0 + exp(-(double)rdec[c])));
        ldsFrq[lc] = (float)(0.10 + 0.9 / (1.0 + exp(-(double)rfrq[c])));
        ldsT1[lc]  = t1a[c];
    }

    // ---- t=0 inline; spikes(0) -> LDS buf0; bits -> L3; prologue in flight ----
    float base2[4][4];
    float mem[4][4], res[4][4];
    unsigned int pooled_pk[4] = {0, 0, 0, 0};
    unsigned long long bal[16];
    const int ax = (llo & 7) << 4;
    char* ring = smem + LDS_RING + w * 12288;
#pragma unroll
    for (int nt = 0; nt < 4; ++nt) {
        int lc = w * 64 + nt * 16 + llo;
        int c = cbase + lc;
        float bb = b_in[c];
        float brv = b_rec[c];
#pragma unroll
        for (int fr = 0; fr < 4; ++fr) {
            int row = lhi * 4 + fr;
            float b0 = __fadd_rn(bacc[nt][fr], bb);
            base2[nt][fr] = __fadd_rn(b0, brv);
            float m_ = __fadd_rn(0.f, b0);
            int s = (m_ > 1.0f) ? 1 : 0;
            res[nt][fr] = 0.f;
            mem[nt][fr] = __fadd_rn(m_, -(float)s);
            pooled_pk[nt] += (unsigned int)s << (8 * fr);
            bal[nt * 4 + fr] = __ballot(s);
            *(unsigned char*)(smem + LDS_SPK0 + ((row * 1024 + c) ^ ((row & 7) << 4))) =
                (unsigned char)s;
        }
    }
    if (lane < 16) {
        unsigned long long rb = 0;
#pragma unroll
        for (int nt = 0; nt < 4; ++nt)
            rb |= ((bal[nt * 4 + (lane & 3)] >> (16 * (lane >> 2))) & 0xFFFFull) << (16 * nt);
        __hip_atomic_store((unsigned long long*)(sx + ((pair * 2 + h) << 10)
                                                 + lane * 64 + w * 8),
                           rb, __ATOMIC_RELAXED, __HIP_MEMORY_SCOPE_AGENT);
    }
    __builtin_amdgcn_sched_barrier(0);
    {   // prologue for t=1 (kt0 slab) — issued AFTER bits store
        const signed char* ib = WrQ + (((size_t)((h * 32 + w * 4) * 3)) << 10) + lane16;
#pragma unroll
        for (int s = 0; s < 12; ++s)
            glds16(ib + s * 1024, ring + s * 1024);
    }
    __builtin_amdgcn_sched_barrier(0);
    asm volatile("s_waitcnt vmcnt(12)" ::: "memory");  // bits store retired; ring in flight
    SBARL();
    if (tid == 0)
        __hip_atomic_store(&flags[pair * 2 + h], 1u,
                           __ATOMIC_RELAXED, __HIP_MEMORY_SCOPE_AGENT);

    // ---- phase C: steps 1..31 ----
    for (int t = 1; t < 32; ++t) {
        if (tid == 0) {
            while (__hip_atomic_load(&flags[(t - 1) * 256 + pair * 2 + (1 - h)],
                                     __ATOMIC_ACQUIRE, __HIP_MEMORY_SCOPE_AGENT) == 0)
                __builtin_amdgcn_s_sleep(2);
        }
        SBAR();
        if (tid < 128) {   // waves 0-1 (their ring over-drains; self-healing counts)
            int row = tid >> 3, pc = tid & 7;
            unsigned long long bits = __hip_atomic_load(
                (unsigned long long*)(sx + ((((t - 1) & 1) * 256 + pair * 2 + (1 - h)) << 10)
                                      + row * 64 + pc * 8),
                __ATOMIC_RELAXED, __HIP_MEMORY_SCOPE_AGENT);
            int sw = (row & 7) << 4;
            char* dst = smem + ((t - 1) & 1) * 16384;
            int kb = pbase + pc * 64;
#pragma unroll
            for (int c4 = 0; c4 < 4; ++c4) {
                unsigned int wb16 = (unsigned int)(bits >> (c4 * 16)) & 0xFFFFu;
                i32x4 v;
#pragma unroll
                for (int q = 0; q < 4; ++q) {
                    unsigned int b4 = (wb16 >> (q * 4)) & 0xFu;
                    v[q] = (int)((b4 & 1u) | ((b4 >> 1) & 1u) << 8 |
                                 ((b4 >> 2) & 1u) << 16 | ((b4 >> 3) & 1u) << 24);
                }
                *(i32x4*)(dst + ((row * 1024 + kb + c4 * 16) ^ sw)) = v;
            }
        }
        SBARL();

        const char* ab = smem + ((t - 1) & 1) * 16384 + llo * 1024;
        char* wbuf = smem + (t & 1) * 16384;

        i32x4 acc[4][3] = {};
        for (int kt = 0; kt < 16; ++kt) {
            i32x4 Af = *(const i32x4*)(ab + ((kt * 64 + lhi * 16) ^ ax));
            if (kt < 15) {
                const signed char* inext =
                    WrQ + (((size_t)(((kt + 1) * 64 + h * 32 + w * 4) * 3)) << 10);
                RING_GROUP(0) RING_GROUP(1) RING_GROUP(2) RING_GROUP(3)
            } else {
                RING_GLAST(0, 9) RING_GLAST(1, 6) RING_GLAST(2, 3) RING_GLAST(3, 0)
            }
        }

        // state update (exact np op order)
#pragma unroll
        for (int nt = 0; nt < 4; ++nt) {
            int lc = w * 64 + nt * 16 + llo;
            int c = cbase + lc;
            float dcc = ldsDec[lc], fqc = ldsFrq[lc], t1c = ldsT1[lc];
#pragma unroll
            for (int fr = 0; fr < 4; ++fr) {
                int row = lhi * 4 + fr;
                float s3 = (float)acc[nt][2][fr];
                float s2 = fmaf(s3, QINV, (float)acc[nt][1][fr]);
                float rec = __fmul_rn(fmaf(s2, QINV, (float)acc[nt][0][fr]), t1c);
                float drive = __fadd_rn(base2[nt][fr], rec);
                float rnew = __fadd_rn(__fmul_rn(dcc, res[nt][fr]),
                                       __fmul_rn(fqc, mem[nt][fr]));
                float tt = __fadd_rn(__fmul_rn(dcc, mem[nt][fr]), drive);
                float m_ = __fadd_rn(tt, -rnew);
                int s = (m_ > 1.0f) ? 1 : 0;
                res[nt][fr] = rnew;
                mem[nt][fr] = __fadd_rn(m_, -(float)s);
                pooled_pk[nt] += (unsigned int)s << (8 * fr);
                if (t < 31) {
                    bal[nt * 4 + fr] = __ballot(s);
                    *(unsigned char*)(wbuf + ((row * 1024 + c) ^ ((row & 7) << 4))) =
                        (unsigned char)s;
                }
            }
        }
        if (t < 31) {
            if (lane < 16) {
                unsigned long long rb = 0;
#pragma unroll
                for (int nt = 0; nt < 4; ++nt)
                    rb |= ((bal[nt * 4 + (lane & 3)] >> (16 * (lane >> 2))) & 0xFFFFull)
                          << (16 * nt);
                __hip_atomic_store((unsigned long long*)(sx + (((t & 1) * 256 + pair * 2 + h) << 10)
                                                         + lane * 64 + w * 8),
                                   rb, __ATOMIC_RELAXED, __HIP_MEMORY_SCOPE_AGENT);
            }
            __builtin_amdgcn_sched_barrier(0);
            {   // next step's kt0 prologue — DMA stays busy through the tail
                const signed char* ib = WrQ + (((size_t)((h * 32 + w * 4) * 3)) << 10) + lane16;
#pragma unroll
                for (int s = 0; s < 12; ++s)
                    glds16(ib + s * 1024, ring + s * 1024);
            }
            __builtin_amdgcn_sched_barrier(0);
            asm volatile("s_waitcnt vmcnt(12)" ::: "memory");  // bits store retired
            SBARL();
            if (tid == 0)
                __hip_atomic_store(&flags[t * 256 + pair * 2 + h], 1u,
                                   __ATOMIC_RELAXED, __HIP_MEMORY_SCOPE_AGENT);
        }
    }

    // ---- phase D ----
    float* plds = (float*)(smem + LDS_PLDS);
#pragma unroll
    for (int nt = 0; nt < 4; ++nt) {
        int lc = w * 64 + nt * 16 + llo;
#pragma unroll
        for (int fr = 0; fr < 4; ++fr)
            plds[(lhi * 4 + fr) * 520 + lc] =
                (float)((pooled_pk[nt] >> (8 * fr)) & 255u) * 0.03125f;
    }
    __syncthreads();
    double part = 0.0;
    if (tid < 256) {
        int row = tid >> 4, o = tid & 15;
        for (int j = 0; j < 512; ++j)
            part += (double)plds[row * 520 + j] * (double)W_out[(size_t)(cbase + j) * 16 + o];
    }
    if (h == 1) {
        if (tid < 256)
            __hip_atomic_store(&pdb[pair * 256 + tid], __double_as_longlong(part),
                               __ATOMIC_RELAXED, __HIP_MEMORY_SCOPE_AGENT);
        __syncthreads();
        if (tid == 0)
            __hip_atomic_store(&flags[32 * 256 + pair * 2 + 1], 1u,
                               __ATOMIC_RELEASE, __HIP_MEMORY_SCOPE_AGENT);
    } else {
        if (tid == 0) {
            while (__hip_atomic_load(&flags[32 * 256 + pair * 2 + 1],
                                     __ATOMIC_ACQUIRE, __HIP_MEMORY_SCOPE_AGENT) == 0)
                __builtin_amdgcn_s_sleep(2);
        }
        __syncthreads();
        if (tid < 256) {
            int row = tid >> 4, o = tid & 15;
            unsigned long long pb = __hip_atomic_load(&pdb[pair * 256 + tid],
                                                      __ATOMIC_RELAXED,
                                                      __HIP_MEMORY_SCOPE_AGENT);
            double tot = part + __longlong_as_double(pb);
            out[(size_t)(r0 + row) * 16 + o] = __fadd_rn((float)tot, b_out[o]);
        }
    }
}

extern "C" void kernel_launch(void* const* d_in, const int* in_sizes, int n_in,
                              void* d_out, int out_size, void* d_ws, size_t ws_size,
                              hipStream_t stream) {
    const float* fused = (const float*)d_in[0];
    const float* W_in  = (const float*)d_in[1];
    const float* b_in  = (const float*)d_in[2];
    const float* W_rec = (const float*)d_in[3];
    const float* b_rec = (const float*)d_in[4];
    const float* W_out = (const float*)d_in[5];
    const float* b_out = (const float*)d_in[6];
    const float* rdec  = (const float*)d_in[7];
    const float* rfrq  = (const float*)d_in[8];

    char* ws = (char*)d_ws;
    signed char*        WrQ   = (signed char*)(ws);
    float*              t1a   = (float*)(ws + 3145728);
    unsigned short*     Wi1   = (unsigned short*)(ws + 3407872);
    unsigned short*     Wi2   = (unsigned short*)(ws + 4980736);
    unsigned short*     Wi3   = (unsigned short*)(ws + 6553600);
    char*               sx    = ws + 8126464;
    unsigned long long* pdb   = (unsigned long long*)(ws + 8650752);
    unsigned int*       flags = (unsigned int*)(ws + 8912896);
    float* out = (float*)d_out;

    hipFuncSetAttribute((const void*)k_main,
                        hipFuncAttributeMaxDynamicSharedMemorySize, LDS_TOTAL);

    hipMemsetAsync(flags, 0, 33 * 256 * 4, stream);
    hipLaunchKernelGGL(k_colmax, dim3(1024), dim3(256), 0, stream, W_rec, t1a);
    hipLaunchKernelGGL(k_packq, dim3(4096), dim3(256), 0, stream, W_rec, t1a, WrQ);
    hipLaunchKernelGGL(k_pack3, dim3(3072), dim3(256), 0, stream, W_in, Wi1, Wi2, Wi3, 768);

    void* args[] = {(void*)&fused, (void*)&Wi1, (void*)&Wi2, (void*)&Wi3, (void*)&b_in,
                    (void*)&WrQ, (void*)&t1a, (void*)&b_rec, (void*)&rdec, (void*)&rfrq,
                    (void*)&W_out, (void*)&b_out, (void*)&sx, (void*)&pdb, (void*)&flags,
                    (void*)&out};
    hipLaunchCooperativeKernel((void*)k_main, dim3(256), dim3(512), args, LDS_TOTAL, stream);
}

// Round 16
// 580.607 us; speedup vs baseline: 1.5535x; 1.1300x over previous
//
#include <hip/hip_runtime.h>

typedef __attribute__((ext_vector_type(4))) float f32x4;
typedef __attribute__((ext_vector_type(4))) int   i32x4;
typedef __attribute__((ext_vector_type(8))) short s16x8;

#define MFMA16(a, b, c)  __builtin_amdgcn_mfma_f32_16x16x32_bf16((a), (b), (c), 0, 0, 0)
#define MFMAI8(a, b, c)  __builtin_amdgcn_mfma_i32_16x16x64_i8((a), (b), (c), 0, 0, 0)

#define QINV (1.0f / 252.0f)

typedef __attribute__((address_space(3))) unsigned int lds_uint;
typedef const __attribute__((address_space(1))) unsigned int glob_uint;
__device__ __forceinline__ void glds16(const void* g, void* l) {
    __builtin_amdgcn_global_load_lds((glob_uint*)g, (lds_uint*)l, 16, 0, 0);
}

#define SBARL()                                                                \
    {                                                                          \
        __builtin_amdgcn_sched_barrier(0);                                     \
        asm volatile("s_waitcnt lgkmcnt(0)" ::: "memory");                     \
        __builtin_amdgcn_s_barrier();                                          \
        __builtin_amdgcn_sched_barrier(0);                                     \
    }
#define SBAR()                                                                 \
    {                                                                          \
        __builtin_amdgcn_sched_barrier(0);                                     \
        __builtin_amdgcn_s_barrier();                                          \
        __builtin_amdgcn_sched_barrier(0);                                     \
    }

// ---------- bf16 helpers (RNE) ----------
__device__ inline unsigned short f2bf(float f) {
    unsigned int u = __float_as_uint(f);
    return (unsigned short)((u + 0x7FFFu + ((u >> 16) & 1u)) >> 16);
}
__device__ inline float bf2f(unsigned short b) {
    return __uint_as_float(((unsigned int)b) << 16);
}

// ---------- pack W [K][1024] f32 -> THREE bf16 levels (W_in path) ----------
__global__ __launch_bounds__(256) void k_pack3(const float* __restrict__ W,
                                               unsigned short* __restrict__ L1,
                                               unsigned short* __restrict__ L2,
                                               unsigned short* __restrict__ L3,
                                               int K) {
    int idx = blockIdx.x * 256 + threadIdx.x;
    if (idx >= K * 1024) return;
    int k = idx >> 10;
    int n = idx & 1023;
    float x = W[idx];
    unsigned short h1 = f2bf(x);  float r1 = x - bf2f(h1);
    unsigned short h2 = f2bf(r1); float r2 = r1 - bf2f(h2);
    unsigned short h3 = f2bf(r2);
    size_t o = ((size_t)(k >> 5) << 15) + ((size_t)n << 5) + (k & 31);
    L1[o] = h1; L2[o] = h2; L3[o] = h3;
}

// ---------- per-column max|W_rec| -> t1[n] = max/126 ----------
__global__ __launch_bounds__(256) void k_colmax(const float* __restrict__ W,
                                                float* __restrict__ t1) {
    __shared__ float red[256];
    int n = blockIdx.x;
    float m = 0.f;
    for (int k = threadIdx.x; k < 1024; k += 256)
        m = fmaxf(m, fabsf(W[(size_t)k * 1024 + n]));
    red[threadIdx.x] = m;
    __syncthreads();
    for (int s = 128; s > 0; s >>= 1) {
        if (threadIdx.x < s) red[threadIdx.x] = fmaxf(red[threadIdx.x], red[threadIdx.x + s]);
        __syncthreads();
    }
    if (threadIdx.x == 0) t1[n] = fmaxf(red[0], 1e-30f) * (1.0f / 126.0f);
}

// ---------- pack W_rec -> 3 i8 digits as MFMA-ready 1KB frags ----------
__global__ __launch_bounds__(256) void k_packq(const float* __restrict__ W,
                                               const float* __restrict__ t1a,
                                               signed char* __restrict__ Q) {
    int idx = blockIdx.x * 256 + threadIdx.x;   // k*1024 + n
    int k = idx >> 10;
    int n = idx & 1023;
    float x = W[idx];
    float T1 = t1a[n];
    float T2 = T1 * QINV;
    float T3 = T2 * QINV;
    float q1 = rintf(x / T1);  float r1 = fmaf(-q1, T1, x);
    float q2 = rintf(r1 / T2); float r2 = fmaf(-q2, T2, r1);
    float q3 = rintf(r2 / T3);
    int kt = k >> 6, cg = n >> 4;
    int lane = (((k >> 4) & 3) << 4) | (n & 15);
    size_t base = ((size_t)((kt * 64 + cg) * 3)) << 10;
    size_t lj = (size_t)lane * 16 + (k & 15);
    Q[base + lj]        = (signed char)(int)q1;
    Q[base + 1024 + lj] = (signed char)(int)q2;
    Q[base + 2048 + lj] = (signed char)(int)q3;
}

// ---------- main: cooperative 256 blocks x 512 thr; quad (4q..4q+3) = rows
// 32q..32q+32; member h owns cols h*256..+256 (0.75 MB WrQ slab/step).
// Spikes exchanged 4-way as raw ballots through L3; single A-LDS buffer. ----
#define FSTR 770
#define LDS_SPK    0        // i8 [32][1024] XOR-swizzled, SINGLE buffer
#define LDS_DEC    32768    // f32[256]
#define LDS_FRQ    33792
#define LDS_T1     34816
#define LDS_RING   35840    // 8 waves x 12288 -> ends 134144
#define LDS_FUSED  35840    // f32 [32][770] = 98560 (phases A/B) -> ends 134400
#define LDS_PLDS   35840    // f32 [32][264] (phase D)
#define LDS_TOTAL  134400

// steady-state group: wait 3 oldest of 12, read 3 B-frags, 6 MFMA (2 M-tiles),
// reissue 3 into same slots from BSRC (kt+2's slab).
#define RING_NT(P, nt, BSRC)                                                   \
    {                                                                          \
        asm volatile("s_waitcnt vmcnt(9)" ::: "memory");                       \
        __builtin_amdgcn_sched_barrier(0);                                     \
        const char* sl = ring + (P) + (nt) * 3072;                             \
        i32x4 Bv0 = *(const i32x4*)(sl + lane16);                              \
        i32x4 Bv1 = *(const i32x4*)(sl + 1024 + lane16);                       \
        i32x4 Bv2 = *(const i32x4*)(sl + 2048 + lane16);                       \
        acc[0][nt][0] = MFMAI8(Af0, Bv0, acc[0][nt][0]);                       \
        acc[1][nt][0] = MFMAI8(Af1, Bv0, acc[1][nt][0]);                       \
        acc[0][nt][1] = MFMAI8(Af0, Bv1, acc[0][nt][1]);                       \
        acc[1][nt][1] = MFMAI8(Af1, Bv1, acc[1][nt][1]);                       \
        acc[0][nt][2] = MFMAI8(Af0, Bv2, acc[0][nt][2]);                       \
        acc[1][nt][2] = MFMAI8(Af1, Bv2, acc[1][nt][2]);                       \
        __builtin_amdgcn_sched_barrier(0);                                     \
        glds16((BSRC),        (void*)sl);                                      \
        glds16((BSRC) + 1024, (void*)(sl + 1024));                             \
        glds16((BSRC) + 2048, (void*)(sl + 2048));                             \
    }
// epilogue group: descending counted wait, no reissue.
#define RING_NTL(P, nt, N)                                                     \
    {                                                                          \
        asm volatile("s_waitcnt vmcnt(" #N ")" ::: "memory");                  \
        __builtin_amdgcn_sched_barrier(0);                                     \
        const char* sl = ring + (P) + (nt) * 3072;                             \
        i32x4 Bv0 = *(const i32x4*)(sl + lane16);                              \
        i32x4 Bv1 = *(const i32x4*)(sl + 1024 + lane16);                       \
        i32x4 Bv2 = *(const i32x4*)(sl + 2048 + lane16);                       \
        acc[0][nt][0] = MFMAI8(Af0, Bv0, acc[0][nt][0]);                       \
        acc[1][nt][0] = MFMAI8(Af1, Bv0, acc[1][nt][0]);                       \
        acc[0][nt][1] = MFMAI8(Af0, Bv1, acc[0][nt][1]);                       \
        acc[1][nt][1] = MFMAI8(Af1, Bv1, acc[1][nt][1]);                       \
        acc[0][nt][2] = MFMAI8(Af0, Bv2, acc[0][nt][2]);                       \
        acc[1][nt][2] = MFMAI8(Af1, Bv2, acc[1][nt][2]);                       \
    }

__global__ __launch_bounds__(512, 2) void k_main(const float* __restrict__ fused,
                                                 const unsigned short* __restrict__ Wi1,
                                                 const unsigned short* __restrict__ Wi2,
                                                 const unsigned short* __restrict__ Wi3,
                                                 const float* __restrict__ b_in,
                                                 const signed char* __restrict__ WrQ,
                                                 const float* __restrict__ t1a,
                                                 const float* __restrict__ b_rec,
                                                 const float* __restrict__ rdec,
                                                 const float* __restrict__ rfrq,
                                                 const float* __restrict__ W_out,
                                                 const float* __restrict__ b_out,
                                                 char* __restrict__ sx,
                                                 unsigned long long* __restrict__ pdb,
                                                 unsigned int* __restrict__ flags,
                                                 float* __restrict__ out) {
    extern __shared__ __align__(16) char smem[];
    const int tid = threadIdx.x;
    const int w = tid >> 6, lane = tid & 63;
    const int llo = lane & 15, lhi = lane >> 4;
    const int bid = blockIdx.x;
    const int q = bid >> 2, h = bid & 3;
    const int r0 = q * 32;
    const int cbase = h * 256;
    const int cg0 = h * 16 + w * 2;        // global col-group of nt=0
    const int lane16 = lane * 16;
    const int ax = (llo & 7) << 4;

    // ---- phase A: stage fused[r0:r0+32][0:768] -> LDS ----
    float* fl = (float*)(smem + LDS_FUSED);
    for (int i = tid; i < 32 * 768; i += 512) {
        int rr = i / 768, cc = i - rr * 768;
        fl[rr * FSTR + cc] = fused[(size_t)(r0 + rr) * 768 + cc];
    }
    __syncthreads();

    // ---- phase B: base for 32 rows x own 256 cols (3x3-level bf16) ----
    f32x4 bacc[2][2] = {};   // [m][nt]
    for (int kt = 0; kt < 24; ++kt) {
        s16x8 a1v[2], a2v[2], a3v[2];
#pragma unroll
        for (int m = 0; m < 2; ++m) {
            const float* ap = fl + (m * 16 + llo) * FSTR + kt * 32 + lhi * 8;
#pragma unroll
            for (int j = 0; j < 8; ++j) {
                float x = ap[j];
                unsigned short h1 = f2bf(x);  float r1 = x - bf2f(h1);
                unsigned short h2 = f2bf(r1); float r2 = r1 - bf2f(h2);
                a1v[m][j] = (short)h1; a2v[m][j] = (short)h2; a3v[m][j] = (short)f2bf(r2);
            }
        }
#pragma unroll
        for (int nt = 0; nt < 2; ++nt) {
            int c = cbase + w * 32 + nt * 16 + llo;
            size_t boff = ((size_t)(kt * 1024 + c) << 5) + lhi * 8;
            s16x8 b1 = *(const s16x8*)&Wi1[boff];
            s16x8 b2 = *(const s16x8*)&Wi2[boff];
            s16x8 b3 = *(const s16x8*)&Wi3[boff];
#pragma unroll
            for (int m = 0; m < 2; ++m) {
                bacc[m][nt] = MFMA16(a1v[m], b1, bacc[m][nt]);
                bacc[m][nt] = MFMA16(a1v[m], b2, bacc[m][nt]);
                bacc[m][nt] = MFMA16(a2v[m], b1, bacc[m][nt]);
                bacc[m][nt] = MFMA16(a2v[m], b2, bacc[m][nt]);
                bacc[m][nt] = MFMA16(a1v[m], b3, bacc[m][nt]);
                bacc[m][nt] = MFMA16(a3v[m], b1, bacc[m][nt]);
            }
        }
    }
    __syncthreads();   // fused dead; ring region free

    // ---- params (own 256 cols) ----
    float* ldsDec = (float*)(smem + LDS_DEC);
    float* ldsFrq = (float*)(smem + LDS_FRQ);
    float* ldsT1  = (float*)(smem + LDS_T1);
    if (tid < 256) {
        int c = cbase + tid;
        ldsDec[tid] = (float)(0.55 + 0.4 / (1.0 + exp(-(double)rdec[c])));
        ldsFrq[tid] = (float)(0.10 + 0.9 / (1.0 + exp(-(double)rfrq[c])));
        ldsT1[tid]  = t1a[c];
    }

    // ---- t=0 inline; ballots -> L3 bits; prologue; flag ----
    float base2[2][2][4];
    float mem[2][2][4], res[2][2][4];
    unsigned int pooled_pk[4] = {0, 0, 0, 0};
    char* ring = smem + LDS_RING + w * 12288;
    unsigned long long myb = 0;
#pragma unroll
    for (int m = 0; m < 2; ++m)
#pragma unroll
        for (int nt = 0; nt < 2; ++nt) {
            int c = cbase + w * 32 + nt * 16 + llo;
            float bb = b_in[c];
            float brv = b_rec[c];
#pragma unroll
            for (int fr = 0; fr < 4; ++fr) {
                float b0 = __fadd_rn(bacc[m][nt][fr], bb);
                base2[m][nt][fr] = __fadd_rn(b0, brv);
                float m_ = __fadd_rn(0.f, b0);
                int s = (m_ > 1.0f) ? 1 : 0;
                res[m][nt][fr] = 0.f;
                mem[m][nt][fr] = __fadd_rn(m_, -(float)s);
                pooled_pk[m * 2 + nt] += (unsigned int)s << (8 * fr);
                unsigned long long b = __ballot(s);
                myb = (lane == (m * 8 + nt * 4 + fr)) ? b : myb;
            }
        }
    if (lane < 16)
        __hip_atomic_store((unsigned long long*)(sx + q * 4096 + h * 1024 + w * 128 + lane * 8),
                           myb, __ATOMIC_RELAXED, __HIP_MEMORY_SCOPE_AGENT);
    __builtin_amdgcn_sched_barrier(0);
    {   // prologue: kt0,kt1 x nt0,nt1 x lvl (consume order)
#pragma unroll
        for (int kk = 0; kk < 2; ++kk)
#pragma unroll
            for (int nt = 0; nt < 2; ++nt) {
                const signed char* b = WrQ + (((size_t)((kk * 64 + cg0 + nt) * 3)) << 10) + lane16;
                char* sl = ring + kk * 6144 + nt * 3072;
                glds16(b,        (void*)sl);
                glds16(b + 1024, (void*)(sl + 1024));
                glds16(b + 2048, (void*)(sl + 2048));
            }
    }
    __builtin_amdgcn_sched_barrier(0);
    asm volatile("s_waitcnt vmcnt(12)" ::: "memory");   // bits (oldest) retired
    SBARL();
    if (tid == 0)
        __hip_atomic_store(&flags[q * 4 + h], 1u,
                           __ATOMIC_RELAXED, __HIP_MEMORY_SCOPE_AGENT);

    // ---- phase C: steps 1..31 ----
    for (int t = 1; t < 32; ++t) {
        if (tid == 0) {
#pragma unroll
            for (int hp = 0; hp < 4; ++hp)
                while (__hip_atomic_load(&flags[(t - 1) * 256 + q * 4 + hp],
                                         __ATOMIC_ACQUIRE, __HIP_MEMORY_SCOPE_AGENT) == 0)
                    __builtin_amdgcn_s_sleep(2);
        }
        SBAR();
        {   // expansion: 512 threads, 1 ballot each -> single A-buffer
            unsigned long long B = __hip_atomic_load(
                (unsigned long long*)(sx + (((t - 1) & 1) * 262144) + q * 4096 + tid * 8),
                __ATOMIC_RELAXED, __HIP_MEMORY_SCOPE_AGENT);
            int fr = tid & 3, nt = (tid >> 2) & 1, m = (tid >> 3) & 1;
            int wsrc = (tid >> 4) & 7, hsrc = tid >> 7;
            int colb = hsrc * 256 + wsrc * 32 + nt * 16;
#pragma unroll
            for (int l2 = 0; l2 < 4; ++l2) {
                int row = m * 16 + l2 * 4 + fr;
                unsigned int b16 = (unsigned int)(B >> (l2 * 16)) & 0xFFFFu;
                i32x4 v;
#pragma unroll
                for (int qq = 0; qq < 4; ++qq) {
                    unsigned int b4 = (b16 >> (qq * 4)) & 0xFu;
                    v[qq] = (int)((b4 & 1u) | ((b4 >> 1) & 1u) << 8 |
                                  ((b4 >> 2) & 1u) << 16 | ((b4 >> 3) & 1u) << 24);
                }
                *(i32x4*)(smem + ((row * 1024 + colb) ^ ((row & 7) << 4))) = v;
            }
        }
        SBARL();

        // kt loop: steady 0..13, epilogue 14..15
        i32x4 acc[2][2][3] = {};
#pragma unroll 2
        for (int kt = 0; kt < 14; ++kt) {
            const int P = (kt & 1) * 6144;
            i32x4 Af0 = *(const i32x4*)(smem + ((llo * 1024 + kt * 64 + lhi * 16) ^ ax));
            i32x4 Af1 = *(const i32x4*)(smem + (((16 + llo) * 1024 + kt * 64 + lhi * 16) ^ ax));
            const signed char* b0 =
                WrQ + (((size_t)(((kt + 2) * 64 + cg0) * 3)) << 10) + lane16;
            const signed char* b1 =
                WrQ + (((size_t)(((kt + 2) * 64 + cg0 + 1) * 3)) << 10) + lane16;
            RING_NT(P, 0, b0)
            RING_NT(P, 1, b1)
        }
        {
            i32x4 Af0 = *(const i32x4*)(smem + ((llo * 1024 + 14 * 64 + lhi * 16) ^ ax));
            i32x4 Af1 = *(const i32x4*)(smem + (((16 + llo) * 1024 + 14 * 64 + lhi * 16) ^ ax));
            RING_NTL(0, 0, 9) RING_NTL(0, 1, 6)
        }
        {
            i32x4 Af0 = *(const i32x4*)(smem + ((llo * 1024 + 15 * 64 + lhi * 16) ^ ax));
            i32x4 Af1 = *(const i32x4*)(smem + (((16 + llo) * 1024 + 15 * 64 + lhi * 16) ^ ax));
            RING_NTL(6144, 0, 3) RING_NTL(6144, 1, 0)
        }

        // state update (exact np op order)
        myb = 0;
#pragma unroll
        for (int m = 0; m < 2; ++m)
#pragma unroll
            for (int nt = 0; nt < 2; ++nt) {
                int lc = w * 32 + nt * 16 + llo;
                float dcc = ldsDec[lc], fqc = ldsFrq[lc], t1c = ldsT1[lc];
#pragma unroll
                for (int fr = 0; fr < 4; ++fr) {
                    float s3 = (float)acc[m][nt][2][fr];
                    float s2 = fmaf(s3, QINV, (float)acc[m][nt][1][fr]);
                    float rec = __fmul_rn(fmaf(s2, QINV, (float)acc[m][nt][0][fr]), t1c);
                    float drive = __fadd_rn(base2[m][nt][fr], rec);
                    float rnew = __fadd_rn(__fmul_rn(dcc, res[m][nt][fr]),
                                           __fmul_rn(fqc, mem[m][nt][fr]));
                    float tt = __fadd_rn(__fmul_rn(dcc, mem[m][nt][fr]), drive);
                    float m_ = __fadd_rn(tt, -rnew);
                    int s = (m_ > 1.0f) ? 1 : 0;
                    res[m][nt][fr] = rnew;
                    mem[m][nt][fr] = __fadd_rn(m_, -(float)s);
                    pooled_pk[m * 2 + nt] += (unsigned int)s << (8 * fr);
                    unsigned long long b = __ballot(s);
                    myb = (lane == (m * 8 + nt * 4 + fr)) ? b : myb;
                }
            }
        if (t < 31) {
            if (lane < 16)
                __hip_atomic_store((unsigned long long*)(sx + ((t & 1) * 262144) + q * 4096
                                                         + h * 1024 + w * 128 + lane * 8),
                                   myb, __ATOMIC_RELAXED, __HIP_MEMORY_SCOPE_AGENT);
            __builtin_amdgcn_sched_barrier(0);
#pragma unroll
            for (int kk = 0; kk < 2; ++kk)
#pragma unroll
                for (int nt = 0; nt < 2; ++nt) {
                    const signed char* b =
                        WrQ + (((size_t)((kk * 64 + cg0 + nt) * 3)) << 10) + lane16;
                    char* sl = ring + kk * 6144 + nt * 3072;
                    glds16(b,        (void*)sl);
                    glds16(b + 1024, (void*)(sl + 1024));
                    glds16(b + 2048, (void*)(sl + 2048));
                }
            __builtin_amdgcn_sched_barrier(0);
            asm volatile("s_waitcnt vmcnt(12)" ::: "memory");
            SBARL();
            if (tid == 0)
                __hip_atomic_store(&flags[t * 256 + q * 4 + h], 1u,
                                   __ATOMIC_RELAXED, __HIP_MEMORY_SCOPE_AGENT);
        }
    }

    // ---- phase D: own-cols f64 partial; h>0 ship; h==0 combine ----
    __syncthreads();
    float* plds = (float*)(smem + LDS_PLDS);
#pragma unroll
    for (int m = 0; m < 2; ++m)
#pragma unroll
        for (int nt = 0; nt < 2; ++nt) {
            int lc = w * 32 + nt * 16 + llo;
#pragma unroll
            for (int fr = 0; fr < 4; ++fr)
                plds[(m * 16 + lhi * 4 + fr) * 264 + lc] =
                    (float)((pooled_pk[m * 2 + nt] >> (8 * fr)) & 255u) * 0.03125f;
        }
    __syncthreads();
    double part = 0.0;
    {
        int row = tid >> 4, o = tid & 15;   // 512 thr = 32 rows x 16 outs
        for (int j = 0; j < 256; ++j)
            part += (double)plds[row * 264 + j] * (double)W_out[(size_t)(cbase + j) * 16 + o];
    }
    if (h != 0) {
        __hip_atomic_store(&pdb[(q * 4 + h) * 512 + tid], __double_as_longlong(part),
                           __ATOMIC_RELAXED, __HIP_MEMORY_SCOPE_AGENT);
        __syncthreads();
        if (tid == 0)
            __hip_atomic_store(&flags[32 * 256 + q * 4 + h], 1u,
                               __ATOMIC_RELEASE, __HIP_MEMORY_SCOPE_AGENT);
    } else {
        if (tid == 0) {
#pragma unroll
            for (int hp = 1; hp < 4; ++hp)
                while (__hip_atomic_load(&flags[32 * 256 + q * 4 + hp],
                                         __ATOMIC_ACQUIRE, __HIP_MEMORY_SCOPE_AGENT) == 0)
                    __builtin_amdgcn_s_sleep(2);
        }
        __syncthreads();
        {
            int row = tid >> 4, o = tid & 15;
            double tot = part;
#pragma unroll
            for (int hp = 1; hp < 4; ++hp) {
                unsigned long long pb = __hip_atomic_load(&pdb[(q * 4 + hp) * 512 + tid],
                                                          __ATOMIC_RELAXED,
                                                          __HIP_MEMORY_SCOPE_AGENT);
                tot += __longlong_as_double(pb);
            }
            out[(size_t)(r0 + row) * 16 + o] = __fadd_rn((float)tot, b_out[o]);
        }
    }
}

extern "C" void kernel_launch(void* const* d_in, const int* in_sizes, int n_in,
                              void* d_out, int out_size, void* d_ws, size_t ws_size,
                              hipStream_t stream) {
    const float* fused = (const float*)d_in[0];
    const float* W_in  = (const float*)d_in[1];
    const float* b_in  = (const float*)d_in[2];
    const float* W_rec = (const float*)d_in[3];
    const float* b_rec = (const float*)d_in[4];
    const float* W_out = (const float*)d_in[5];
    const float* b_out = (const float*)d_in[6];
    const float* rdec  = (const float*)d_in[7];
    const float* rfrq  = (const float*)d_in[8];

    // ws: WrQ 3MB | t1 | Wi1/2/3 4.5MB | sx 512KB | pdb 1MB | flags 33KB (~9.7MB)
    char* ws = (char*)d_ws;
    signed char*        WrQ   = (signed char*)(ws);
    float*              t1a   = (float*)(ws + 3145728);
    unsigned short*     Wi1   = (unsigned short*)(ws + 3407872);
    unsigned short*     Wi2   = (unsigned short*)(ws + 4980736);
    unsigned short*     Wi3   = (unsigned short*)(ws + 6553600);
    char*               sx    = ws + 8126464;
    unsigned long long* pdb   = (unsigned long long*)(ws + 8650752);
    unsigned int*       flags = (unsigned int*)(ws + 9699328);
    float* out = (float*)d_out;

    hipFuncSetAttribute((const void*)k_main,
                        hipFuncAttributeMaxDynamicSharedMemorySize, LDS_TOTAL);

    hipMemsetAsync(flags, 0, 33 * 256 * 4, stream);
    hipLaunchKernelGGL(k_colmax, dim3(1024), dim3(256), 0, stream, W_rec, t1a);
    hipLaunchKernelGGL(k_packq, dim3(4096), dim3(256), 0, stream, W_rec, t1a, WrQ);
    hipLaunchKernelGGL(k_pack3, dim3(3072), dim3(256), 0, stream, W_in, Wi1, Wi2, Wi3, 768);

    void* args[] = {(void*)&fused, (void*)&Wi1, (void*)&Wi2, (void*)&Wi3, (void*)&b_in,
                    (void*)&WrQ, (void*)&t1a, (void*)&b_rec, (void*)&rdec, (void*)&rfrq,
                    (void*)&W_out, (void*)&b_out, (void*)&sx, (void*)&pdb, (void*)&flags,
                    (void*)&out};
    hipLaunchCooperativeKernel((void*)k_main, dim3(256), dim3(512), args, LDS_TOTAL, stream);
}

// Round 17
// 444.925 us; speedup vs baseline: 2.0273x; 1.3050x over previous
//
#include <hip/hip_runtime.h>

typedef __attribute__((ext_vector_type(4))) float f32x4;
typedef __attribute__((ext_vector_type(4))) int   i32x4;
typedef __attribute__((ext_vector_type(8))) short s16x8;

#define MFMA16(a, b, c)  __builtin_amdgcn_mfma_f32_16x16x32_bf16((a), (b), (c), 0, 0, 0)
#define MFMAI8(a, b, c)  __builtin_amdgcn_mfma_i32_16x16x64_i8((a), (b), (c), 0, 0, 0)

#define QINV (1.0f / 252.0f)

typedef __attribute__((address_space(3))) unsigned int lds_uint;
typedef const __attribute__((address_space(1))) unsigned int glob_uint;
__device__ __forceinline__ void glds16(const void* g, void* l) {
    __builtin_amdgcn_global_load_lds((glob_uint*)g, (lds_uint*)l, 16, 0, 0);
}

#define SBARL()                                                                \
    {                                                                          \
        __builtin_amdgcn_sched_barrier(0);                                     \
        asm volatile("s_waitcnt lgkmcnt(0)" ::: "memory");                     \
        __builtin_amdgcn_s_barrier();                                          \
        __builtin_amdgcn_sched_barrier(0);                                     \
    }
#define SBAR()                                                                 \
    {                                                                          \
        __builtin_amdgcn_sched_barrier(0);                                     \
        __builtin_amdgcn_s_barrier();                                          \
        __builtin_amdgcn_sched_barrier(0);                                     \
    }

// ---------- bf16 helpers (RNE) ----------
__device__ inline unsigned short f2bf(float f) {
    unsigned int u = __float_as_uint(f);
    return (unsigned short)((u + 0x7FFFu + ((u >> 16) & 1u)) >> 16);
}
__device__ inline float bf2f(unsigned short b) {
    return __uint_as_float(((unsigned int)b) << 16);
}

// ---------- pack W [K][1024] f32 -> THREE bf16 levels (W_in path) ----------
__global__ __launch_bounds__(256) void k_pack3(const float* __restrict__ W,
                                               unsigned short* __restrict__ L1,
                                               unsigned short* __restrict__ L2,
                                               unsigned short* __restrict__ L3,
                                               int K) {
    int idx = blockIdx.x * 256 + threadIdx.x;
    if (idx >= K * 1024) return;
    int k = idx >> 10;
    int n = idx & 1023;
    float x = W[idx];
    unsigned short h1 = f2bf(x);  float r1 = x - bf2f(h1);
    unsigned short h2 = f2bf(r1); float r2 = r1 - bf2f(h2);
    unsigned short h3 = f2bf(r2);
    size_t o = ((size_t)(k >> 5) << 15) + ((size_t)n << 5) + (k & 31);
    L1[o] = h1; L2[o] = h2; L3[o] = h3;
}

// ---------- per-column max|W_rec| -> t1[n] = max/126 ----------
__global__ __launch_bounds__(256) void k_colmax(const float* __restrict__ W,
                                                float* __restrict__ t1) {
    __shared__ float red[256];
    int n = blockIdx.x;
    float m = 0.f;
    for (int k = threadIdx.x; k < 1024; k += 256)
        m = fmaxf(m, fabsf(W[(size_t)k * 1024 + n]));
    red[threadIdx.x] = m;
    __syncthreads();
    for (int s = 128; s > 0; s >>= 1) {
        if (threadIdx.x < s) red[threadIdx.x] = fmaxf(red[threadIdx.x], red[threadIdx.x + s]);
        __syncthreads();
    }
    if (threadIdx.x == 0) t1[n] = fmaxf(red[0], 1e-30f) * (1.0f / 126.0f);
}

// ---------- pack W_rec -> 3 i8 digits as MFMA-ready 1KB frags ----------
__global__ __launch_bounds__(256) void k_packq(const float* __restrict__ W,
                                               const float* __restrict__ t1a,
                                               signed char* __restrict__ Q) {
    int idx = blockIdx.x * 256 + threadIdx.x;   // k*1024 + n
    int k = idx >> 10;
    int n = idx & 1023;
    float x = W[idx];
    float T1 = t1a[n];
    float T2 = T1 * QINV;
    float T3 = T2 * QINV;
    float q1 = rintf(x / T1);  float r1 = fmaf(-q1, T1, x);
    float q2 = rintf(r1 / T2); float r2 = fmaf(-q2, T2, r1);
    float q3 = rintf(r2 / T3);
    int kt = k >> 6, cg = n >> 4;
    int lane = (((k >> 4) & 3) << 4) | (n & 15);
    size_t base = ((size_t)((kt * 64 + cg) * 3)) << 10;
    size_t lj = (size_t)lane * 16 + (k & 15);
    Q[base + lj]        = (signed char)(int)q1;
    Q[base + 1024 + lj] = (signed char)(int)q2;
    Q[base + 2048 + lj] = (signed char)(int)q3;
}

// ---------- main: cooperative 256 blocks x 512 thr; quad rows 32q..+32,
// member h cols h*256..+256. Cyclic kt order (own kts first) hides the
// pairwise L3 spike exchange under own-spike MFMAs. ----------
#define FSTR 770
#define LDS_SPK    0        // i8 [32][1024] XOR-swizzled, SINGLE buffer
#define LDS_DEC    32768
#define LDS_FRQ    33792
#define LDS_T1     34816
#define LDS_RING   35840    // 8 waves x 12288 -> ends 134144
#define LDS_FUSED  35840    // f32 [32][770] (phases A/B only)
#define LDS_PLDS   35840    // f32 [32][264] (phase D)
#define LDS_TOTAL  134400

#define RING_NT(P, nt, BSRC)                                                   \
    {                                                                          \
        asm volatile("s_waitcnt vmcnt(9)" ::: "memory");                       \
        __builtin_amdgcn_sched_barrier(0);                                     \
        const char* sl = ring + (P) + (nt) * 3072;                             \
        i32x4 Bv0 = *(const i32x4*)(sl + lane16);                              \
        i32x4 Bv1 = *(const i32x4*)(sl + 1024 + lane16);                       \
        i32x4 Bv2 = *(const i32x4*)(sl + 2048 + lane16);                       \
        acc[0][nt][0] = MFMAI8(Af0, Bv0, acc[0][nt][0]);                       \
        acc[1][nt][0] = MFMAI8(Af1, Bv0, acc[1][nt][0]);                       \
        acc[0][nt][1] = MFMAI8(Af0, Bv1, acc[0][nt][1]);                       \
        acc[1][nt][1] = MFMAI8(Af1, Bv1, acc[1][nt][1]);                       \
        acc[0][nt][2] = MFMAI8(Af0, Bv2, acc[0][nt][2]);                       \
        acc[1][nt][2] = MFMAI8(Af1, Bv2, acc[1][nt][2]);                       \
        __builtin_amdgcn_sched_barrier(0);                                     \
        glds16((BSRC),        (void*)sl);                                      \
        glds16((BSRC) + 1024, (void*)(sl + 1024));                             \
        glds16((BSRC) + 2048, (void*)(sl + 2048));                             \
    }
#define RING_NTL(P, nt, N)                                                     \
    {                                                                          \
        asm volatile("s_waitcnt vmcnt(" #N ")" ::: "memory");                  \
        __builtin_amdgcn_sched_barrier(0);                                     \
        const char* sl = ring + (P) + (nt) * 3072;                             \
        i32x4 Bv0 = *(const i32x4*)(sl + lane16);                              \
        i32x4 Bv1 = *(const i32x4*)(sl + 1024 + lane16);                       \
        i32x4 Bv2 = *(const i32x4*)(sl + 2048 + lane16);                       \
        acc[0][nt][0] = MFMAI8(Af0, Bv0, acc[0][nt][0]);                       \
        acc[1][nt][0] = MFMAI8(Af1, Bv0, acc[1][nt][0]);                       \
        acc[0][nt][1] = MFMAI8(Af0, Bv1, acc[0][nt][1]);                       \
        acc[1][nt][1] = MFMAI8(Af1, Bv1, acc[1][nt][1]);                       \
        acc[0][nt][2] = MFMAI8(Af0, Bv2, acc[0][nt][2]);                       \
        acc[1][nt][2] = MFMAI8(Af1, Bv2, acc[1][nt][2]);                       \
    }

__global__ __launch_bounds__(512, 2) void k_main(const float* __restrict__ fused,
                                                 const unsigned short* __restrict__ Wi1,
                                                 const unsigned short* __restrict__ Wi2,
                                                 const unsigned short* __restrict__ Wi3,
                                                 const float* __restrict__ b_in,
                                                 const signed char* __restrict__ WrQ,
                                                 const float* __restrict__ t1a,
                                                 const float* __restrict__ b_rec,
                                                 const float* __restrict__ rdec,
                                                 const float* __restrict__ rfrq,
                                                 const float* __restrict__ W_out,
                                                 const float* __restrict__ b_out,
                                                 char* __restrict__ sx,
                                                 unsigned long long* __restrict__ pdb,
                                                 unsigned int* __restrict__ flags,
                                                 float* __restrict__ out) {
    extern __shared__ __align__(16) char smem[];
    const int tid = threadIdx.x;
    const int w = tid >> 6, lane = tid & 63;
    const int llo = lane & 15, lhi = lane >> 4;
    const int bid = blockIdx.x;
    const int q = bid >> 2, h = bid & 3;
    const int r0 = q * 32;
    const int cbase = h * 256;
    const int cg0 = h * 16 + w * 2;
    const int lane16 = lane * 16;
    const int ax = (llo & 7) << 4;

    // ---- phase A: stage fused[r0:r0+32][0:768] -> LDS ----
    float* fl = (float*)(smem + LDS_FUSED);
    for (int i = tid; i < 32 * 768; i += 512) {
        int rr = i / 768, cc = i - rr * 768;
        fl[rr * FSTR + cc] = fused[(size_t)(r0 + rr) * 768 + cc];
    }
    __syncthreads();

    // ---- phase B: base for 32 rows x own 256 cols (3x3-level bf16) ----
    f32x4 bacc[2][2] = {};   // [m][nt]
    for (int kt = 0; kt < 24; ++kt) {
        s16x8 a1v[2], a2v[2], a3v[2];
#pragma unroll
        for (int m = 0; m < 2; ++m) {
            const float* ap = fl + (m * 16 + llo) * FSTR + kt * 32 + lhi * 8;
#pragma unroll
            for (int j = 0; j < 8; ++j) {
                float x = ap[j];
                unsigned short h1 = f2bf(x);  float r1 = x - bf2f(h1);
                unsigned short h2 = f2bf(r1); float r2 = r1 - bf2f(h2);
                a1v[m][j] = (short)h1; a2v[m][j] = (short)h2; a3v[m][j] = (short)f2bf(r2);
            }
        }
#pragma unroll
        for (int nt = 0; nt < 2; ++nt) {
            int c = cbase + w * 32 + nt * 16 + llo;
            size_t boff = ((size_t)(kt * 1024 + c) << 5) + lhi * 8;
            s16x8 b1 = *(const s16x8*)&Wi1[boff];
            s16x8 b2 = *(const s16x8*)&Wi2[boff];
            s16x8 b3 = *(const s16x8*)&Wi3[boff];
#pragma unroll
            for (int m = 0; m < 2; ++m) {
                bacc[m][nt] = MFMA16(a1v[m], b1, bacc[m][nt]);
                bacc[m][nt] = MFMA16(a1v[m], b2, bacc[m][nt]);
                bacc[m][nt] = MFMA16(a2v[m], b1, bacc[m][nt]);
                bacc[m][nt] = MFMA16(a2v[m], b2, bacc[m][nt]);
                bacc[m][nt] = MFMA16(a1v[m], b3, bacc[m][nt]);
                bacc[m][nt] = MFMA16(a3v[m], b1, bacc[m][nt]);
            }
        }
    }
    __syncthreads();   // fused dead

    // ---- params (own 256 cols) ----
    float* ldsDec = (float*)(smem + LDS_DEC);
    float* ldsFrq = (float*)(smem + LDS_FRQ);
    float* ldsT1  = (float*)(smem + LDS_T1);
    if (tid < 256) {
        int c = cbase + tid;
        ldsDec[tid] = (float)(0.55 + 0.4 / (1.0 + exp(-(double)rdec[c])));
        ldsFrq[tid] = (float)(0.10 + 0.9 / (1.0 + exp(-(double)rfrq[c])));
        ldsT1[tid]  = t1a[c];
    }

    // ---- t=0 inline; own spikes DIRECT to A-LDS; ballots -> L3; prologue ----
    float base2[2][2][4];
    float mem[2][2][4], res[2][2][4];
    unsigned int pooled_pk[4] = {0, 0, 0, 0};
    char* ring = smem + LDS_RING + w * 12288;
    unsigned long long myb = 0;
#pragma unroll
    for (int m = 0; m < 2; ++m)
#pragma unroll
        for (int nt = 0; nt < 2; ++nt) {
            int c = cbase + w * 32 + nt * 16 + llo;
            float bb = b_in[c];
            float brv = b_rec[c];
#pragma unroll
            for (int fr = 0; fr < 4; ++fr) {
                int row = m * 16 + lhi * 4 + fr;
                float b0 = __fadd_rn(bacc[m][nt][fr], bb);
                base2[m][nt][fr] = __fadd_rn(b0, brv);
                float m_ = __fadd_rn(0.f, b0);
                int s = (m_ > 1.0f) ? 1 : 0;
                res[m][nt][fr] = 0.f;
                mem[m][nt][fr] = __fadd_rn(m_, -(float)s);
                pooled_pk[m * 2 + nt] += (unsigned int)s << (8 * fr);
                unsigned long long b = __ballot(s);
                myb = (lane == (m * 8 + nt * 4 + fr)) ? b : myb;
                *(unsigned char*)(smem + ((row * 1024 + c) ^ ((row & 7) << 4))) =
                    (unsigned char)s;
            }
        }
    if (lane < 16)
        __hip_atomic_store((unsigned long long*)(sx + q * 4096 + h * 1024 + w * 128 + lane * 8),
                           myb, __ATOMIC_RELAXED, __HIP_MEMORY_SCOPE_AGENT);
    __builtin_amdgcn_sched_barrier(0);
    {   // prologue: kt_seq[0]=4h, kt_seq[1]=4h+1
#pragma unroll
        for (int kk = 0; kk < 2; ++kk)
#pragma unroll
            for (int nt = 0; nt < 2; ++nt) {
                const signed char* b =
                    WrQ + (((size_t)(((4 * h + kk) * 64 + cg0 + nt) * 3)) << 10) + lane16;
                char* sl = ring + kk * 6144 + nt * 3072;
                glds16(b,        (void*)sl);
                glds16(b + 1024, (void*)(sl + 1024));
                glds16(b + 2048, (void*)(sl + 2048));
            }
    }
    __builtin_amdgcn_sched_barrier(0);
    asm volatile("s_waitcnt vmcnt(12)" ::: "memory");   // bits (oldest) retired
    SBARL();
    if (tid == 0)
        __hip_atomic_store(&flags[q * 4 + h], 1u,
                           __ATOMIC_RELAXED, __HIP_MEMORY_SCOPE_AGENT);

    // ---- phase C: steps 1..31 ----
    for (int t = 1; t < 32; ++t) {
        i32x4 acc[2][2][3] = {};

        // i = 0..3: OWN kts (kt = 4h+i) — no partner data needed
#pragma unroll
        for (int i = 0; i < 4; ++i) {
            const int kt = 4 * h + i;
            const int P = (i & 1) * 6144;
            i32x4 Af0 = *(const i32x4*)(smem + ((llo * 1024 + kt * 64 + lhi * 16) ^ ax));
            i32x4 Af1 = *(const i32x4*)(smem + (((16 + llo) * 1024 + kt * 64 + lhi * 16) ^ ax));
            const int nkt = (kt + 2) & 15;
            const signed char* b0 = WrQ + (((size_t)((nkt * 64 + cg0) * 3)) << 10) + lane16;
            const signed char* b1 = WrQ + (((size_t)((nkt * 64 + cg0 + 1) * 3)) << 10) + lane16;
            RING_NT(P, 0, b0)
            RING_NT(P, 1, b1)
        }

        // poll partner flags in parallel (own flag set in our tail)
        if (tid < 4 && tid != h) {
            while (__hip_atomic_load(&flags[(t - 1) * 256 + q * 4 + tid],
                                     __ATOMIC_ACQUIRE, __HIP_MEMORY_SCOPE_AGENT) == 0)
                __builtin_amdgcn_s_sleep(2);
        }
        SBAR();
        // expand the 384 PARTNER ballots only
        if (tid < 384) {
            int hh = tid >> 7;
            int hsrc = hh + (hh >= h ? 1 : 0);
            int inner = tid & 127;
            unsigned long long B = __hip_atomic_load(
                (unsigned long long*)(sx + (((t - 1) & 1) * 262144) + q * 4096
                                      + hsrc * 1024 + inner * 8),
                __ATOMIC_RELAXED, __HIP_MEMORY_SCOPE_AGENT);
            int l = inner & 15, wsrc = inner >> 4;
            int fr = l & 3, nt = (l >> 2) & 1, m = (l >> 3) & 1;
            int colb = hsrc * 256 + wsrc * 32 + nt * 16;
#pragma unroll
            for (int l2 = 0; l2 < 4; ++l2) {
                int row = m * 16 + l2 * 4 + fr;
                unsigned int b16 = (unsigned int)(B >> (l2 * 16)) & 0xFFFFu;
                i32x4 v;
#pragma unroll
                for (int qq = 0; qq < 4; ++qq) {
                    unsigned int b4 = (b16 >> (qq * 4)) & 0xFu;
                    v[qq] = (int)((b4 & 1u) | ((b4 >> 1) & 1u) << 8 |
                                  ((b4 >> 2) & 1u) << 16 | ((b4 >> 3) & 1u) << 24);
                }
                *(i32x4*)(smem + ((row * 1024 + colb) ^ ((row & 7) << 4))) = v;
            }
        }
        SBARL();

        // i = 4..13 steady (partner kts), 14..15 epilogue
#pragma unroll 2
        for (int i = 4; i < 14; ++i) {
            const int kt = (4 * h + i) & 15;
            const int P = (i & 1) * 6144;
            i32x4 Af0 = *(const i32x4*)(smem + ((llo * 1024 + kt * 64 + lhi * 16) ^ ax));
            i32x4 Af1 = *(const i32x4*)(smem + (((16 + llo) * 1024 + kt * 64 + lhi * 16) ^ ax));
            const int nkt = (4 * h + i + 2) & 15;
            const signed char* b0 = WrQ + (((size_t)((nkt * 64 + cg0) * 3)) << 10) + lane16;
            const signed char* b1 = WrQ + (((size_t)((nkt * 64 + cg0 + 1) * 3)) << 10) + lane16;
            RING_NT(P, 0, b0)
            RING_NT(P, 1, b1)
        }
        {
            const int kt = (4 * h + 14) & 15;
            i32x4 Af0 = *(const i32x4*)(smem + ((llo * 1024 + kt * 64 + lhi * 16) ^ ax));
            i32x4 Af1 = *(const i32x4*)(smem + (((16 + llo) * 1024 + kt * 64 + lhi * 16) ^ ax));
            RING_NTL(0, 0, 9) RING_NTL(0, 1, 6)
        }
        {
            const int kt = (4 * h + 15) & 15;
            i32x4 Af0 = *(const i32x4*)(smem + ((llo * 1024 + kt * 64 + lhi * 16) ^ ax));
            i32x4 Af1 = *(const i32x4*)(smem + (((16 + llo) * 1024 + kt * 64 + lhi * 16) ^ ax));
            RING_NTL(6144, 0, 3) RING_NTL(6144, 1, 0)
        }

        // state update (exact np op order); own spikes DIRECT to A (t<31)
        myb = 0;
#pragma unroll
        for (int m = 0; m < 2; ++m)
#pragma unroll
            for (int nt = 0; nt < 2; ++nt) {
                int lc = w * 32 + nt * 16 + llo;
                int c = cbase + lc;
                float dcc = ldsDec[lc], fqc = ldsFrq[lc], t1c = ldsT1[lc];
#pragma unroll
                for (int fr = 0; fr < 4; ++fr) {
                    int row = m * 16 + lhi * 4 + fr;
                    float s3 = (float)acc[m][nt][2][fr];
                    float s2 = fmaf(s3, QINV, (float)acc[m][nt][1][fr]);
                    float rec = __fmul_rn(fmaf(s2, QINV, (float)acc[m][nt][0][fr]), t1c);
                    float drive = __fadd_rn(base2[m][nt][fr], rec);
                    float rnew = __fadd_rn(__fmul_rn(dcc, res[m][nt][fr]),
                                           __fmul_rn(fqc, mem[m][nt][fr]));
                    float tt = __fadd_rn(__fmul_rn(dcc, mem[m][nt][fr]), drive);
                    float m_ = __fadd_rn(tt, -rnew);
                    int s = (m_ > 1.0f) ? 1 : 0;
                    res[m][nt][fr] = rnew;
                    mem[m][nt][fr] = __fadd_rn(m_, -(float)s);
                    pooled_pk[m * 2 + nt] += (unsigned int)s << (8 * fr);
                    unsigned long long b = __ballot(s);
                    myb = (lane == (m * 8 + nt * 4 + fr)) ? b : myb;
                    if (t < 31)
                        *(unsigned char*)(smem + ((row * 1024 + c) ^ ((row & 7) << 4))) =
                            (unsigned char)s;
                }
            }
        if (t < 31) {
            if (lane < 16)
                __hip_atomic_store((unsigned long long*)(sx + ((t & 1) * 262144) + q * 4096
                                                         + h * 1024 + w * 128 + lane * 8),
                                   myb, __ATOMIC_RELAXED, __HIP_MEMORY_SCOPE_AGENT);
            __builtin_amdgcn_sched_barrier(0);
#pragma unroll
            for (int kk = 0; kk < 2; ++kk)
#pragma unroll
                for (int nt = 0; nt < 2; ++nt) {
                    const signed char* b =
                        WrQ + (((size_t)(((4 * h + kk) * 64 + cg0 + nt) * 3)) << 10) + lane16;
                    char* sl = ring + kk * 6144 + nt * 3072;
                    glds16(b,        (void*)sl);
                    glds16(b + 1024, (void*)(sl + 1024));
                    glds16(b + 2048, (void*)(sl + 2048));
                }
            __builtin_amdgcn_sched_barrier(0);
            asm volatile("s_waitcnt vmcnt(12)" ::: "memory");
            SBARL();
            if (tid == 0)
                __hip_atomic_store(&flags[t * 256 + q * 4 + h], 1u,
                                   __ATOMIC_RELAXED, __HIP_MEMORY_SCOPE_AGENT);
        }
    }

    // ---- phase D: own-cols f64 partial; h>0 ship; h==0 combine ----
    __syncthreads();
    float* plds = (float*)(smem + LDS_PLDS);
#pragma unroll
    for (int m = 0; m < 2; ++m)
#pragma unroll
        for (int nt = 0; nt < 2; ++nt) {
            int lc = w * 32 + nt * 16 + llo;
#pragma unroll
            for (int fr = 0; fr < 4; ++fr)
                plds[(m * 16 + lhi * 4 + fr) * 264 + lc] =
                    (float)((pooled_pk[m * 2 + nt] >> (8 * fr)) & 255u) * 0.03125f;
        }
    __syncthreads();
    double part = 0.0;
    {
        int row = tid >> 4, o = tid & 15;
        for (int j = 0; j < 256; ++j)
            part += (double)plds[row * 264 + j] * (double)W_out[(size_t)(cbase + j) * 16 + o];
    }
    if (h != 0) {
        __hip_atomic_store(&pdb[(q * 4 + h) * 512 + tid], __double_as_longlong(part),
                           __ATOMIC_RELAXED, __HIP_MEMORY_SCOPE_AGENT);
        __syncthreads();
        if (tid == 0)
            __hip_atomic_store(&flags[32 * 256 + q * 4 + h], 1u,
                               __ATOMIC_RELEASE, __HIP_MEMORY_SCOPE_AGENT);
    } else {
        if (tid == 0) {
#pragma unroll
            for (int hp = 1; hp < 4; ++hp)
                while (__hip_atomic_load(&flags[32 * 256 + q * 4 + hp],
                                         __ATOMIC_ACQUIRE, __HIP_MEMORY_SCOPE_AGENT) == 0)
                    __builtin_amdgcn_s_sleep(2);
        }
        __syncthreads();
        {
            int row = tid >> 4, o = tid & 15;
            double tot = part;
#pragma unroll
            for (int hp = 1; hp < 4; ++hp) {
                unsigned long long pb = __hip_atomic_load(&pdb[(q * 4 + hp) * 512 + tid],
                                                          __ATOMIC_RELAXED,
                                                          __HIP_MEMORY_SCOPE_AGENT);
                tot += __longlong_as_double(pb);
            }
            out[(size_t)(r0 + row) * 16 + o] = __fadd_rn((float)tot, b_out[o]);
        }
    }
}

extern "C" void kernel_launch(void* const* d_in, const int* in_sizes, int n_in,
                              void* d_out, int out_size, void* d_ws, size_t ws_size,
                              hipStream_t stream) {
    const float* fused = (const float*)d_in[0];
    const float* W_in  = (const float*)d_in[1];
    const float* b_in  = (const float*)d_in[2];
    const float* W_rec = (const float*)d_in[3];
    const float* b_rec = (const float*)d_in[4];
    const float* W_out = (const float*)d_in[5];
    const float* b_out = (const float*)d_in[6];
    const float* rdec  = (const float*)d_in[7];
    const float* rfrq  = (const float*)d_in[8];

    char* ws = (char*)d_ws;
    signed char*        WrQ   = (signed char*)(ws);
    float*              t1a   = (float*)(ws + 3145728);
    unsigned short*     Wi1   = (unsigned short*)(ws + 3407872);
    unsigned short*     Wi2   = (unsigned short*)(ws + 4980736);
    unsigned short*     Wi3   = (unsigned short*)(ws + 6553600);
    char*               sx    = ws + 8126464;
    unsigned long long* pdb   = (unsigned long long*)(ws + 8650752);
    unsigned int*       flags = (unsigned int*)(ws + 9699328);
    float* out = (float*)d_out;

    hipFuncSetAttribute((const void*)k_main,
                        hipFuncAttributeMaxDynamicSharedMemorySize, LDS_TOTAL);

    hipMemsetAsync(flags, 0, 33 * 256 * 4, stream);
    hipLaunchKernelGGL(k_colmax, dim3(1024), dim3(256), 0, stream, W_rec, t1a);
    hipLaunchKernelGGL(k_packq, dim3(4096), dim3(256), 0, stream, W_rec, t1a, WrQ);
    hipLaunchKernelGGL(k_pack3, dim3(3072), dim3(256), 0, stream, W_in, Wi1, Wi2, Wi3, 768);

    void* args[] = {(void*)&fused, (void*)&Wi1, (void*)&Wi2, (void*)&Wi3, (void*)&b_in,
                    (void*)&WrQ, (void*)&t1a, (void*)&b_rec, (void*)&rdec, (void*)&rfrq,
                    (void*)&W_out, (void*)&b_out, (void*)&sx, (void*)&pdb, (void*)&flags,
                    (void*)&out};
    hipLaunchCooperativeKernel((void*)k_main, dim3(256), dim3(512), args, LDS_TOTAL, stream);
}